// Round 1
// baseline (1361.660 us; speedup 1.0000x reference)
//
#include <hip/hip_runtime.h>

#define BATCH 100000
#define VECBASE 51200000  // BATCH*512 floats; start of vectors_out region in d_out

typedef float fl4  __attribute__((ext_vector_type(4)));
typedef float f32x4 __attribute__((ext_vector_type(4)));
typedef short s16x4 __attribute__((ext_vector_type(4)));
typedef short s16x8 __attribute__((ext_vector_type(8)));

__device__ __forceinline__ short f2bf(float f) {
  unsigned int u = __float_as_uint(f);
  u += 0x7fffu + ((u >> 16) & 1u);
  return (short)(u >> 16);
}

// ---------------------------------------------------------------------------
// K0: one-time per-launch transpose of Wf [656][512] -> WfT bf16 [512][656]
//     and Wg [512][128] -> WgT bf16 [128][512]. Writes coalesced.
__global__ void transpose_w(const float* __restrict__ Wf, const float* __restrict__ Wg,
                            short* __restrict__ WfT, short* __restrict__ WgT) {
  int gid = blockIdx.x * 256 + threadIdx.x;
  if (gid < 512 * 656) {
    int n = gid / 656, k = gid - n * 656;
    WfT[gid] = f2bf(Wf[k * 512 + n]);
  } else {
    int g2 = gid - 512 * 656;
    if (g2 < 128 * 512) {
      int n = g2 >> 9, k = g2 & 511;
      WgT[g2] = f2bf(Wg[k * 128 + n]);
    }
  }
}

// ---------------------------------------------------------------------------
// K1: geometric stage. 16 rows/block, 256 threads.
// Computes Vh (128x3), Vcp (32x3), cross -> Vh_cat (144x3), sh (144, bf16->ws),
// Vu (128x3, f32 -> d_out vectors region; gating applied later in-place).
__global__ void vec_stage(const float* __restrict__ vecs,
                          const float* __restrict__ Wh,
                          const float* __restrict__ Wcp,
                          const float* __restrict__ Wu,
                          short* __restrict__ sh_ws,
                          float* __restrict__ out) {
  __shared__ float s_vh[16 * 480];   // [r][o<160][c]  (o in [0,144) = Vh_cat after cross)
  __shared__ float s_buf[144 * 48];  // phase1: vecT [v][r][c]; phase2: vh_catT [k][r][c]
  const int t = threadIdx.x;
  const int row0 = blockIdx.x << 4;

  // load 16 rows of vectors, transpose to [v][r][c]
  for (int i = t; i < 16 * 384; i += 256) {
    int r = i / 384;
    int j = i - r * 384;
    int v = j / 3, c = j - v * 3;
    s_buf[v * 48 + r * 3 + c] = vecs[row0 * 384 + i];
  }
  __syncthreads();

  {  // Vh: o = t&127 over 128 outs, g = t>>7 picks rows g*8..g*8+7
    const int o = t & 127, g = t >> 7;
    float acc[8][3];
#pragma unroll
    for (int r = 0; r < 8; ++r) { acc[r][0] = 0.f; acc[r][1] = 0.f; acc[r][2] = 0.f; }
    for (int v = 0; v < 128; ++v) {
      float w = Wh[v * 128 + o];
      const float* pv = &s_buf[v * 48 + g * 24];
#pragma unroll
      for (int r = 0; r < 8; ++r) {
        acc[r][0] = fmaf(w, pv[r * 3 + 0], acc[r][0]);
        acc[r][1] = fmaf(w, pv[r * 3 + 1], acc[r][1]);
        acc[r][2] = fmaf(w, pv[r * 3 + 2], acc[r][2]);
      }
    }
#pragma unroll
    for (int r = 0; r < 8; ++r) {
      s_vh[(g * 8 + r) * 480 + o * 3 + 0] = acc[r][0];
      s_vh[(g * 8 + r) * 480 + o * 3 + 1] = acc[r][1];
      s_vh[(g * 8 + r) * 480 + o * 3 + 2] = acc[r][2];
    }
  }
  {  // Vcp: o = t&31 over 32 outs, g = t>>5 picks rows g*2, g*2+1; stored at o+128
    const int o = t & 31, g = t >> 5;
    float a0[3] = {0.f, 0.f, 0.f}, a1[3] = {0.f, 0.f, 0.f};
    for (int v = 0; v < 128; ++v) {
      float w = Wcp[v * 32 + o];
      const float* pv = &s_buf[v * 48 + g * 6];
      a0[0] = fmaf(w, pv[0], a0[0]); a0[1] = fmaf(w, pv[1], a0[1]); a0[2] = fmaf(w, pv[2], a0[2]);
      a1[0] = fmaf(w, pv[3], a1[0]); a1[1] = fmaf(w, pv[4], a1[1]); a1[2] = fmaf(w, pv[5], a1[2]);
    }
#pragma unroll
    for (int c = 0; c < 3; ++c) {
      s_vh[(g * 2 + 0) * 480 + (128 + o) * 3 + c] = a0[c];
      s_vh[(g * 2 + 1) * 480 + (128 + o) * 3 + c] = a1[c];
    }
  }
  __syncthreads();
  {  // cross(Vcp[:, :16], Vcp[:, 16:]) -> slot 128+p  (16 rows x 16 p = 256 threads)
    const int r = t >> 4, p = t & 15;
    float ax = s_vh[r * 480 + (128 + p) * 3 + 0];
    float ay = s_vh[r * 480 + (128 + p) * 3 + 1];
    float az = s_vh[r * 480 + (128 + p) * 3 + 2];
    float bx = s_vh[r * 480 + (144 + p) * 3 + 0];
    float by = s_vh[r * 480 + (144 + p) * 3 + 1];
    float bz = s_vh[r * 480 + (144 + p) * 3 + 2];
    s_vh[r * 480 + (128 + p) * 3 + 0] = ay * bz - az * by;
    s_vh[r * 480 + (128 + p) * 3 + 1] = az * bx - ax * bz;
    s_vh[r * 480 + (128 + p) * 3 + 2] = ax * by - ay * bx;
  }
  __syncthreads();
  // sh + transpose Vh_cat into s_buf [k][r][c]
  for (int i = t; i < 16 * 144; i += 256) {
    int r = i / 144, k = i - r * 144;
    float x = s_vh[r * 480 + k * 3 + 0];
    float y = s_vh[r * 480 + k * 3 + 1];
    float z = s_vh[r * 480 + k * 3 + 2];
    s_buf[k * 48 + r * 3 + 0] = x;
    s_buf[k * 48 + r * 3 + 1] = y;
    s_buf[k * 48 + r * 3 + 2] = z;
    sh_ws[(row0 + r) * 144 + k] = f2bf(sqrtf(fmaxf(x * x + y * y + z * z, 1e-8f)));
  }
  __syncthreads();
  {  // Vu: o = t&127, g = t>>7 -> rows g*8..g*8+7; write f32 Vu into d_out vectors region
    const int o = t & 127, g = t >> 7;
    float acc[8][3];
#pragma unroll
    for (int r = 0; r < 8; ++r) { acc[r][0] = 0.f; acc[r][1] = 0.f; acc[r][2] = 0.f; }
    for (int k = 0; k < 144; ++k) {
      float w = Wu[k * 128 + o];
      const float* pv = &s_buf[k * 48 + g * 24];
#pragma unroll
      for (int r = 0; r < 8; ++r) {
        acc[r][0] = fmaf(w, pv[r * 3 + 0], acc[r][0]);
        acc[r][1] = fmaf(w, pv[r * 3 + 1], acc[r][1]);
        acc[r][2] = fmaf(w, pv[r * 3 + 2], acc[r][2]);
      }
    }
#pragma unroll
    for (int r = 0; r < 8; ++r) {
      int orow = row0 + g * 8 + r;
      float* po = &out[VECBASE + ((size_t)orow * 128 + o) * 3];
      po[0] = acc[r][0]; po[1] = acc[r][1]; po[2] = acc[r][2];
    }
  }
}

// ---------------------------------------------------------------------------
// K2: feats_out = silu(concat(feats, sh) @ Wf + bf).  M=100000, K=656, N=512.
// 128x128 tile, 4 waves (2x2), 16x16x32 bf16 MFMA, BK=32, reg-staged A (f32->bf16
// convert; sh part already bf16), B staged from pre-transposed WfT.
__global__ void gemm_feats(const float* __restrict__ feats,
                           const short* __restrict__ sh_ws,
                           const short* __restrict__ WfT,
                           const float* __restrict__ bfv,
                           float* __restrict__ out) {
  const int bid = blockIdx.x;
  const int mt = bid >> 2, nt = bid & 3;  // consecutive bids share mt -> A L2 reuse
  const int row0 = mt << 7, n0 = nt << 7;
  const int t = threadIdx.x;
  const int lane = t & 63, wv = t >> 6;
  const int wr = wv >> 1, wc = wv & 1;
  const int lr = lane & 15, lk = lane >> 4;
  __shared__ short Al[128 * 40];  // [row][k] bf16, row pitch 40 (bank de-phase)
  __shared__ short Bl[128 * 40];  // [n][k]  bf16
  f32x4 acc[4][4];
#pragma unroll
  for (int i = 0; i < 4; ++i)
#pragma unroll
    for (int j = 0; j < 4; ++j) acc[i][j] = (f32x4){0.f, 0.f, 0.f, 0.f};

  for (int ks = 0; ks < 21; ++ks) {
    const int k0 = ks << 5;
    __syncthreads();
    // stage A: 128 rows x 32 k
#pragma unroll
    for (int it = 0; it < 4; ++it) {
      int idx = t + (it << 8);
      int r = idx >> 3, ch = idx & 7;
      int grow = row0 + r;
      int kc = k0 + (ch << 2);
      s16x4 q = (s16x4){0, 0, 0, 0};
      if (grow < BATCH) {
        if (kc < 512) {
          fl4 v = *reinterpret_cast<const fl4*>(&feats[(size_t)grow * 512 + kc]);
          q[0] = f2bf(v[0]); q[1] = f2bf(v[1]); q[2] = f2bf(v[2]); q[3] = f2bf(v[3]);
        } else if (kc < 656) {
          q = *reinterpret_cast<const s16x4*>(&sh_ws[(size_t)grow * 144 + (kc - 512)]);
        }
      }
      *reinterpret_cast<s16x4*>(&Al[r * 40 + (ch << 2)]) = q;
    }
    // stage B: 128 n-rows x 32 k from WfT[n][k]
#pragma unroll
    for (int it = 0; it < 2; ++it) {
      int idx = t + (it << 8);
      int n = idx >> 2, c8 = idx & 3;
      int kk = k0 + (c8 << 3);
      s16x8 q;
      if (kk < 656) q = *reinterpret_cast<const s16x8*>(&WfT[(n0 + n) * 656 + kk]);
      else          q = (s16x8){0, 0, 0, 0, 0, 0, 0, 0};
      *reinterpret_cast<s16x8*>(&Bl[n * 40 + (c8 << 3)]) = q;
    }
    __syncthreads();
    s16x8 af[4], bq[4];
#pragma unroll
    for (int mi = 0; mi < 4; ++mi)
      af[mi] = *reinterpret_cast<const s16x8*>(&Al[((wr << 6) + (mi << 4) + lr) * 40 + (lk << 3)]);
#pragma unroll
    for (int ni = 0; ni < 4; ++ni)
      bq[ni] = *reinterpret_cast<const s16x8*>(&Bl[((wc << 6) + (ni << 4) + lr) * 40 + (lk << 3)]);
#pragma unroll
    for (int mi = 0; mi < 4; ++mi)
#pragma unroll
      for (int ni = 0; ni < 4; ++ni)
        acc[mi][ni] = __builtin_amdgcn_mfma_f32_16x16x32_bf16(af[mi], bq[ni], acc[mi][ni], 0, 0, 0);
  }
  // epilogue: silu(x + bias) -> d_out feats region (f32)
#pragma unroll
  for (int ni = 0; ni < 4; ++ni) {
    int col = n0 + (wc << 6) + (ni << 4) + lr;
    float bb = bfv[col];
#pragma unroll
    for (int mi = 0; mi < 4; ++mi) {
      int rbase = row0 + (wr << 6) + (mi << 4) + (lk << 2);
#pragma unroll
      for (int r = 0; r < 4; ++r) {
        int grow = rbase + r;
        if (grow < BATCH) {
          float x = acc[mi][ni][r] + bb;
          out[(size_t)grow * 512 + col] = x / (1.f + __expf(-x));
        }
      }
    }
  }
}

// ---------------------------------------------------------------------------
// K3: gating = feats_out @ Wg + bg; vectors_out = sigmoid(gating) * Vu (in-place
// rescale of the Vu values K1 left in the d_out vectors region). M=100000, K=512, N=128.
__global__ void gemm_gate(const float* __restrict__ fo,
                          const short* __restrict__ WgT,
                          const float* __restrict__ bg,
                          float* __restrict__ out) {
  const int row0 = blockIdx.x << 7;
  const int t = threadIdx.x;
  const int lane = t & 63, wv = t >> 6;
  const int wr = wv >> 1, wc = wv & 1;
  const int lr = lane & 15, lk = lane >> 4;
  __shared__ short Al[128 * 40];
  __shared__ short Bl[128 * 40];
  f32x4 acc[4][4];
#pragma unroll
  for (int i = 0; i < 4; ++i)
#pragma unroll
    for (int j = 0; j < 4; ++j) acc[i][j] = (f32x4){0.f, 0.f, 0.f, 0.f};

  for (int ks = 0; ks < 16; ++ks) {
    const int k0 = ks << 5;
    __syncthreads();
#pragma unroll
    for (int it = 0; it < 4; ++it) {
      int idx = t + (it << 8);
      int r = idx >> 3, ch = idx & 7;
      int grow = row0 + r;
      int kc = k0 + (ch << 2);
      s16x4 q = (s16x4){0, 0, 0, 0};
      if (grow < BATCH) {
        fl4 v = *reinterpret_cast<const fl4*>(&fo[(size_t)grow * 512 + kc]);
        q[0] = f2bf(v[0]); q[1] = f2bf(v[1]); q[2] = f2bf(v[2]); q[3] = f2bf(v[3]);
      }
      *reinterpret_cast<s16x4*>(&Al[r * 40 + (ch << 2)]) = q;
    }
#pragma unroll
    for (int it = 0; it < 2; ++it) {
      int idx = t + (it << 8);
      int n = idx >> 2, c8 = idx & 3;
      int kk = k0 + (c8 << 3);
      s16x8 q = *reinterpret_cast<const s16x8*>(&WgT[n * 512 + kk]);
      *reinterpret_cast<s16x8*>(&Bl[n * 40 + (c8 << 3)]) = q;
    }
    __syncthreads();
    s16x8 af[4], bq[4];
#pragma unroll
    for (int mi = 0; mi < 4; ++mi)
      af[mi] = *reinterpret_cast<const s16x8*>(&Al[((wr << 6) + (mi << 4) + lr) * 40 + (lk << 3)]);
#pragma unroll
    for (int ni = 0; ni < 4; ++ni)
      bq[ni] = *reinterpret_cast<const s16x8*>(&Bl[((wc << 6) + (ni << 4) + lr) * 40 + (lk << 3)]);
#pragma unroll
    for (int mi = 0; mi < 4; ++mi)
#pragma unroll
      for (int ni = 0; ni < 4; ++ni)
        acc[mi][ni] = __builtin_amdgcn_mfma_f32_16x16x32_bf16(af[mi], bq[ni], acc[mi][ni], 0, 0, 0);
  }
#pragma unroll
  for (int ni = 0; ni < 4; ++ni) {
    int col = (wc << 6) + (ni << 4) + lr;
    float bb = bg[col];
#pragma unroll
    for (int mi = 0; mi < 4; ++mi) {
      int rbase = row0 + (wr << 6) + (mi << 4) + (lk << 2);
#pragma unroll
      for (int r = 0; r < 4; ++r) {
        int grow = rbase + r;
        if (grow < BATCH) {
          float x = acc[mi][ni][r] + bb;
          float gate = 1.f / (1.f + __expf(-x));
          float* pv = &out[VECBASE + ((size_t)grow * 128 + col) * 3];
          pv[0] *= gate; pv[1] *= gate; pv[2] *= gate;
        }
      }
    }
  }
}

// ---------------------------------------------------------------------------
extern "C" void kernel_launch(void* const* d_in, const int* in_sizes, int n_in,
                              void* d_out, int out_size, void* d_ws, size_t ws_size,
                              hipStream_t stream) {
  const float* feats = (const float*)d_in[0];
  const float* vecs  = (const float*)d_in[1];
  const float* Wh    = (const float*)d_in[2];
  const float* Wcp   = (const float*)d_in[3];
  const float* Wu    = (const float*)d_in[4];
  const float* Wf    = (const float*)d_in[5];
  const float* bfv   = (const float*)d_in[6];
  const float* Wg    = (const float*)d_in[7];
  const float* bg    = (const float*)d_in[8];
  float* out = (float*)d_out;

  char* ws = (char*)d_ws;
  short* sh_ws = (short*)ws;                          // 100000*144*2 = 28,800,000 B
  short* WfT   = (short*)(ws + 28800000);             // 512*656*2   =    671,744 B
  short* WgT   = (short*)(ws + 28800000 + 671744);    // 128*512*2   =    131,072 B

  hipLaunchKernelGGL(transpose_w, dim3(1568), dim3(256), 0, stream, Wf, Wg, WfT, WgT);
  hipLaunchKernelGGL(vec_stage,   dim3(6250), dim3(256), 0, stream, vecs, Wh, Wcp, Wu, sh_ws, out);
  hipLaunchKernelGGL(gemm_feats,  dim3(3128), dim3(256), 0, stream, feats, sh_ws, WfT, bfv, out);
  hipLaunchKernelGGL(gemm_gate,   dim3(782),  dim3(256), 0, stream, out, WgT, bg, out);
}

// Round 2
// 955.336 us; speedup vs baseline: 1.4253x; 1.4253x over previous
//
#include <hip/hip_runtime.h>

#define BATCH 100000
#define M3 300000            // 3*BATCH rows
#define VECBASE 51200000     // BATCH*512 floats; start of vectors_out region in d_out

typedef float fl4  __attribute__((ext_vector_type(4)));
typedef float f32x4 __attribute__((ext_vector_type(4)));
typedef short s16x4 __attribute__((ext_vector_type(4)));
typedef short s16x8 __attribute__((ext_vector_type(8)));

__device__ __forceinline__ short f2bf(float f) {
  unsigned int u = __float_as_uint(f);
  u += 0x7fffu + ((u >> 16) & 1u);
  return (short)(u >> 16);
}
__device__ __forceinline__ float bf2f(short s) {
  return __uint_as_float(((unsigned int)(unsigned short)s) << 16);
}

// ---------------------------------------------------------------------------
// K0: weight prep (bf16 transposes, one-shot, ~0.4M elements)
//  WB1 [160][128]: n<128 -> Wh[k][n], else Wcp[k][n-128]
//  WuTp [128][160]: Wu[k][o] for k<144 else 0
//  WfT [512][656], WgT [128][512]
__global__ __launch_bounds__(256) void prep_w(
    const float* __restrict__ Wh, const float* __restrict__ Wcp,
    const float* __restrict__ Wu, const float* __restrict__ Wf,
    const float* __restrict__ Wg, short* __restrict__ WB1,
    short* __restrict__ WuTp, short* __restrict__ WfT, short* __restrict__ WgT) {
  int gid = blockIdx.x * 256 + threadIdx.x;
  if (gid < 20480) {                       // WB1
    int n = gid >> 7, k = gid & 127;
    WB1[gid] = f2bf(n < 128 ? Wh[k * 128 + n] : Wcp[k * 32 + (n - 128)]);
  } else if (gid < 40960) {                // WuTp
    int i = gid - 20480;
    int o = i / 160, k = i - o * 160;
    WuTp[i] = k < 144 ? f2bf(Wu[k * 128 + o]) : (short)0;
  } else if (gid < 40960 + 335872) {       // WfT
    int i = gid - 40960;
    int n = i / 656, k = i - n * 656;
    WfT[i] = f2bf(Wf[k * 512 + n]);
  } else if (gid < 40960 + 335872 + 65536) {  // WgT
    int i = gid - (40960 + 335872);
    int n = i >> 9, k = i & 511;
    WgT[i] = f2bf(Wg[k * 128 + n]);
  }
}

// ---------------------------------------------------------------------------
// K1: geo GEMM1.  D[3B][160] = A[3B][128] @ WB1^T, A row r=b*3+c, A[r][v]=vecs[b][v][c].
// Tile 192 rows (=64 b) x 160 cols, 4 waves (2x2: 96x80 each), K=128 staged once.
// cols 0..127 -> Vcat bf16; cols 128..159 -> Vcpf f32 (cross-product precision).
__global__ __launch_bounds__(256) void geo_gemm1(
    const float* __restrict__ vecs, const short* __restrict__ WB1,
    short* __restrict__ Vcat, float* __restrict__ Vcpf) {
  __shared__ short Al[192 * 128];          // row pitch 256B (mult of 128 -> XOR-safe)
  const int t = threadIdx.x;
  const int b0 = blockIdx.x * 64;
  const int row0 = blockIdx.x * 192;

  // stage A: contiguous global loads, LDS scatter (b-aligned tile)
#pragma unroll
  for (int it = 0; it < 24; ++it) {
    int fj = (it * 256 + t) * 4;           // float index within 64-b chunk
    int bl = fj / 384;
    int rem = fj - bl * 384;
    int v = rem / 3, c = rem - v * 3;
    fl4 val = (fl4){0.f, 0.f, 0.f, 0.f};
    int b = b0 + bl;
    if (b < BATCH) val = *reinterpret_cast<const fl4*>(&vecs[(size_t)b * 384 + rem]);
#pragma unroll
    for (int e = 0; e < 4; ++e) {
      int row = bl * 3 + c;
      int off = (row << 8) + (v << 1);
      *(short*)((char*)Al + (off ^ ((row & 7) << 4))) = f2bf(val[e]);
      if (++c == 3) { c = 0; ++v; }
    }
  }
  __syncthreads();

  const int lane = t & 63, wv = t >> 6;
  const int wr = wv >> 1, wc = wv & 1;
  const int lr = lane & 15, lk = lane >> 4;
  f32x4 acc[6][5];
#pragma unroll
  for (int i = 0; i < 6; ++i)
#pragma unroll
    for (int j = 0; j < 5; ++j) acc[i][j] = (f32x4){0.f, 0.f, 0.f, 0.f};

#pragma unroll
  for (int kk = 0; kk < 4; ++kk) {
    s16x8 af[6], bq[5];
#pragma unroll
    for (int mi = 0; mi < 6; ++mi) {
      int row = wr * 96 + mi * 16 + lr;
      int off = (row << 8) + (kk << 6) + (lk << 4);
      af[mi] = *(const s16x8*)((const char*)Al + (off ^ ((row & 7) << 4)));
    }
#pragma unroll
    for (int ni = 0; ni < 5; ++ni)
      bq[ni] = *reinterpret_cast<const s16x8*>(
          &WB1[(wc * 80 + ni * 16 + lr) * 128 + (kk << 5) + (lk << 3)]);
#pragma unroll
    for (int mi = 0; mi < 6; ++mi)
#pragma unroll
      for (int ni = 0; ni < 5; ++ni)
        acc[mi][ni] = __builtin_amdgcn_mfma_f32_16x16x32_bf16(af[mi], bq[ni], acc[mi][ni], 0, 0, 0);
  }

#pragma unroll
  for (int mi = 0; mi < 6; ++mi)
#pragma unroll
    for (int ni = 0; ni < 5; ++ni) {
      int col = wc * 80 + ni * 16 + lr;
#pragma unroll
      for (int r = 0; r < 4; ++r) {
        int row = row0 + wr * 96 + mi * 16 + lk * 4 + r;
        if (row < M3) {
          if (col < 128) Vcat[(size_t)row * 160 + col] = f2bf(acc[mi][ni][r]);
          else           Vcpf[(size_t)row * 32 + (col - 128)] = acc[mi][ni][r];
        }
      }
    }
}

// ---------------------------------------------------------------------------
// K2: cross products (f32 inputs from Vcpf) + clamped norms -> sh bf16.
// One thread per b; contiguous per-thread spans give full line utilization.
__global__ __launch_bounds__(256) void cross_norm(
    const float* __restrict__ Vcpf, short* __restrict__ Vcat,
    short* __restrict__ sh_ws) {
  int b = blockIdx.x * 256 + threadIdx.x;
  if (b >= BATCH) return;
  const float* cpf = &Vcpf[(size_t)b * 96];     // rows 3b..3b+2, 32 each
  short* vr = &Vcat[(size_t)b * 480];           // rows 3b..3b+2, 160 each
  float cx[16], cy[16], cz[16];
#pragma unroll
  for (int p = 0; p < 16; ++p) {
    float ax = cpf[p],      ay = cpf[32 + p],      az = cpf[64 + p];
    float bx = cpf[16 + p], by = cpf[48 + p],      bz = cpf[80 + p];
    cx[p] = ay * bz - az * by;
    cy[p] = az * bx - ax * bz;
    cz[p] = ax * by - ay * bx;
  }
  // write cp (bf16) into cols 128..143, zeros into 144..159 of the 3 rows
#pragma unroll
  for (int p = 0; p < 16; ++p) {
    vr[128 + p]       = f2bf(cx[p]);
    vr[160 + 128 + p] = f2bf(cy[p]);
    vr[320 + 128 + p] = f2bf(cz[p]);
    vr[144 + p] = 0; vr[160 + 144 + p] = 0; vr[320 + 144 + p] = 0;
  }
  // sh over k=0..127 from bf16 Vh rows, k=128..143 from f32 cp regs
  short* shp = &sh_ws[(size_t)b * 144];
#pragma unroll
  for (int kb = 0; kb < 16; ++kb) {
    s16x8 r0 = *reinterpret_cast<const s16x8*>(&vr[kb * 8]);
    s16x8 r1 = *reinterpret_cast<const s16x8*>(&vr[160 + kb * 8]);
    s16x8 r2 = *reinterpret_cast<const s16x8*>(&vr[320 + kb * 8]);
    s16x8 o;
#pragma unroll
    for (int j = 0; j < 8; ++j) {
      float x = bf2f(r0[j]), y = bf2f(r1[j]), z = bf2f(r2[j]);
      o[j] = f2bf(sqrtf(fmaxf(x * x + y * y + z * z, 1e-8f)));
    }
    *reinterpret_cast<s16x8*>(&shp[kb * 8]) = o;
  }
#pragma unroll
  for (int p = 0; p < 16; ++p)
    shp[128 + p] = f2bf(sqrtf(fmaxf(cx[p] * cx[p] + cy[p] * cy[p] + cz[p] * cz[p], 1e-8f)));
}

// ---------------------------------------------------------------------------
// K3: Vu GEMM.  Vu[3B][128] = Vcat[3B][160(K,zero-padded)] @ WuTp^T.
// Tile 128x128, 4 waves 2x2 (64x64), K=160 staged once. Writes f32 Vu scattered
// into d_out vectors region [b][o][c]; gating rescales in place later.
__global__ __launch_bounds__(256) void geo_gemm2(
    const short* __restrict__ Vcat, const short* __restrict__ WuTp,
    float* __restrict__ out) {
  __shared__ short Al[128 * 192];          // row pitch 384B (mult of 128 -> XOR-safe)
  const int t = threadIdx.x;
  const int row0 = blockIdx.x << 7;
#pragma unroll
  for (int it = 0; it < 10; ++it) {
    int idx = it * 256 + t;                // 2560 chunks of 8
    int r = idx / 20, ch = idx - r * 20;
    int grow = row0 + r;
    s16x8 q = (s16x8){0, 0, 0, 0, 0, 0, 0, 0};
    if (grow < M3) q = *reinterpret_cast<const s16x8*>(&Vcat[(size_t)grow * 160 + ch * 8]);
    int off = r * 384 + ch * 16;
    *(s16x8*)((char*)Al + (off ^ ((r & 7) << 4))) = q;
  }
  __syncthreads();

  const int lane = t & 63, wv = t >> 6;
  const int wr = wv >> 1, wc = wv & 1;
  const int lr = lane & 15, lk = lane >> 4;
  f32x4 acc[4][4];
#pragma unroll
  for (int i = 0; i < 4; ++i)
#pragma unroll
    for (int j = 0; j < 4; ++j) acc[i][j] = (f32x4){0.f, 0.f, 0.f, 0.f};

#pragma unroll
  for (int kk = 0; kk < 5; ++kk) {
    s16x8 af[4], bq[4];
#pragma unroll
    for (int mi = 0; mi < 4; ++mi) {
      int row = wr * 64 + mi * 16 + lr;
      int off = row * 384 + (kk << 6) + (lk << 4);
      af[mi] = *(const s16x8*)((const char*)Al + (off ^ ((row & 7) << 4)));
    }
#pragma unroll
    for (int ni = 0; ni < 4; ++ni)
      bq[ni] = *reinterpret_cast<const s16x8*>(
          &WuTp[(wc * 64 + ni * 16 + lr) * 160 + (kk << 5) + (lk << 3)]);
#pragma unroll
    for (int mi = 0; mi < 4; ++mi)
#pragma unroll
      for (int ni = 0; ni < 4; ++ni)
        acc[mi][ni] = __builtin_amdgcn_mfma_f32_16x16x32_bf16(af[mi], bq[ni], acc[mi][ni], 0, 0, 0);
  }
#pragma unroll
  for (int mi = 0; mi < 4; ++mi)
#pragma unroll
    for (int ni = 0; ni < 4; ++ni) {
      int col = wc * 64 + ni * 16 + lr;
#pragma unroll
      for (int r = 0; r < 4; ++r) {
        int row = row0 + wr * 64 + mi * 16 + lk * 4 + r;
        if (row < M3) {
          int b = row / 3, c = row - b * 3;
          out[VECBASE + ((size_t)b * 128 + col) * 3 + c] = acc[mi][ni][r];
        }
      }
    }
}

// ---------------------------------------------------------------------------
// K4: feats_out = silu(concat(feats, sh) @ Wf + bf).  M=100000, K=656, N=512.
__global__ __launch_bounds__(256) void gemm_feats(
    const float* __restrict__ feats, const short* __restrict__ sh_ws,
    const short* __restrict__ WfT, const float* __restrict__ bfv,
    float* __restrict__ out) {
  const int bid = blockIdx.x;
  const int mt = bid >> 2, nt = bid & 3;
  const int row0 = mt << 7, n0 = nt << 7;
  const int t = threadIdx.x;
  const int lane = t & 63, wv = t >> 6;
  const int wr = wv >> 1, wc = wv & 1;
  const int lr = lane & 15, lk = lane >> 4;
  __shared__ short Al[128 * 40];
  __shared__ short Bl[128 * 40];
  f32x4 acc[4][4];
#pragma unroll
  for (int i = 0; i < 4; ++i)
#pragma unroll
    for (int j = 0; j < 4; ++j) acc[i][j] = (f32x4){0.f, 0.f, 0.f, 0.f};

  for (int ks = 0; ks < 21; ++ks) {
    const int k0 = ks << 5;
    __syncthreads();
#pragma unroll
    for (int it = 0; it < 4; ++it) {
      int idx = t + (it << 8);
      int r = idx >> 3, ch = idx & 7;
      int grow = row0 + r;
      int kc = k0 + (ch << 2);
      s16x4 q = (s16x4){0, 0, 0, 0};
      if (grow < BATCH) {
        if (kc < 512) {
          fl4 v = *reinterpret_cast<const fl4*>(&feats[(size_t)grow * 512 + kc]);
          q[0] = f2bf(v[0]); q[1] = f2bf(v[1]); q[2] = f2bf(v[2]); q[3] = f2bf(v[3]);
        } else if (kc < 656) {
          q = *reinterpret_cast<const s16x4*>(&sh_ws[(size_t)grow * 144 + (kc - 512)]);
        }
      }
      *reinterpret_cast<s16x4*>(&Al[r * 40 + (ch << 2)]) = q;
    }
#pragma unroll
    for (int it = 0; it < 2; ++it) {
      int idx = t + (it << 8);
      int n = idx >> 2, c8 = idx & 3;
      int kk = k0 + (c8 << 3);
      s16x8 q;
      if (kk < 656) q = *reinterpret_cast<const s16x8*>(&WfT[(n0 + n) * 656 + kk]);
      else          q = (s16x8){0, 0, 0, 0, 0, 0, 0, 0};
      *reinterpret_cast<s16x8*>(&Bl[n * 40 + (c8 << 3)]) = q;
    }
    __syncthreads();
    s16x8 af[4], bq[4];
#pragma unroll
    for (int mi = 0; mi < 4; ++mi)
      af[mi] = *reinterpret_cast<const s16x8*>(&Al[((wr << 6) + (mi << 4) + lr) * 40 + (lk << 3)]);
#pragma unroll
    for (int ni = 0; ni < 4; ++ni)
      bq[ni] = *reinterpret_cast<const s16x8*>(&Bl[((wc << 6) + (ni << 4) + lr) * 40 + (lk << 3)]);
#pragma unroll
    for (int mi = 0; mi < 4; ++mi)
#pragma unroll
      for (int ni = 0; ni < 4; ++ni)
        acc[mi][ni] = __builtin_amdgcn_mfma_f32_16x16x32_bf16(af[mi], bq[ni], acc[mi][ni], 0, 0, 0);
  }
#pragma unroll
  for (int ni = 0; ni < 4; ++ni) {
    int col = n0 + (wc << 6) + (ni << 4) + lr;
    float bb = bfv[col];
#pragma unroll
    for (int mi = 0; mi < 4; ++mi) {
      int rbase = row0 + (wr << 6) + (mi << 4) + (lk << 2);
#pragma unroll
      for (int r = 0; r < 4; ++r) {
        int grow = rbase + r;
        if (grow < BATCH) {
          float x = acc[mi][ni][r] + bb;
          out[(size_t)grow * 512 + col] = x / (1.f + __expf(-x));
        }
      }
    }
  }
}

// ---------------------------------------------------------------------------
// K5: gating GEMM + in-place sigmoid*Vu rescale.  M=100000, K=512, N=128.
__global__ __launch_bounds__(256) void gemm_gate(
    const float* __restrict__ fo, const short* __restrict__ WgT,
    const float* __restrict__ bg, float* __restrict__ out) {
  const int row0 = blockIdx.x << 7;
  const int t = threadIdx.x;
  const int lane = t & 63, wv = t >> 6;
  const int wr = wv >> 1, wc = wv & 1;
  const int lr = lane & 15, lk = lane >> 4;
  __shared__ short Al[128 * 40];
  __shared__ short Bl[128 * 40];
  f32x4 acc[4][4];
#pragma unroll
  for (int i = 0; i < 4; ++i)
#pragma unroll
    for (int j = 0; j < 4; ++j) acc[i][j] = (f32x4){0.f, 0.f, 0.f, 0.f};

  for (int ks = 0; ks < 16; ++ks) {
    const int k0 = ks << 5;
    __syncthreads();
#pragma unroll
    for (int it = 0; it < 4; ++it) {
      int idx = t + (it << 8);
      int r = idx >> 3, ch = idx & 7;
      int grow = row0 + r;
      int kc = k0 + (ch << 2);
      s16x4 q = (s16x4){0, 0, 0, 0};
      if (grow < BATCH) {
        fl4 v = *reinterpret_cast<const fl4*>(&fo[(size_t)grow * 512 + kc]);
        q[0] = f2bf(v[0]); q[1] = f2bf(v[1]); q[2] = f2bf(v[2]); q[3] = f2bf(v[3]);
      }
      *reinterpret_cast<s16x4*>(&Al[r * 40 + (ch << 2)]) = q;
    }
#pragma unroll
    for (int it = 0; it < 2; ++it) {
      int idx = t + (it << 8);
      int n = idx >> 2, c8 = idx & 3;
      int kk = k0 + (c8 << 3);
      s16x8 q = *reinterpret_cast<const s16x8*>(&WgT[n * 512 + kk]);
      *reinterpret_cast<s16x8*>(&Bl[n * 40 + (c8 << 3)]) = q;
    }
    __syncthreads();
    s16x8 af[4], bq[4];
#pragma unroll
    for (int mi = 0; mi < 4; ++mi)
      af[mi] = *reinterpret_cast<const s16x8*>(&Al[((wr << 6) + (mi << 4) + lr) * 40 + (lk << 3)]);
#pragma unroll
    for (int ni = 0; ni < 4; ++ni)
      bq[ni] = *reinterpret_cast<const s16x8*>(&Bl[((wc << 6) + (ni << 4) + lr) * 40 + (lk << 3)]);
#pragma unroll
    for (int mi = 0; mi < 4; ++mi)
#pragma unroll
      for (int ni = 0; ni < 4; ++ni)
        acc[mi][ni] = __builtin_amdgcn_mfma_f32_16x16x32_bf16(af[mi], bq[ni], acc[mi][ni], 0, 0, 0);
  }
#pragma unroll
  for (int ni = 0; ni < 4; ++ni) {
    int col = (wc << 6) + (ni << 4) + lr;
    float bb = bg[col];
#pragma unroll
    for (int mi = 0; mi < 4; ++mi) {
      int rbase = row0 + (wr << 6) + (mi << 4) + (lk << 2);
#pragma unroll
      for (int r = 0; r < 4; ++r) {
        int grow = rbase + r;
        if (grow < BATCH) {
          float x = acc[mi][ni][r] + bb;
          float gate = 1.f / (1.f + __expf(-x));
          float* pv = &out[VECBASE + ((size_t)grow * 128 + col) * 3];
          pv[0] *= gate; pv[1] *= gate; pv[2] *= gate;
        }
      }
    }
  }
}

// ---------------------------------------------------------------------------
extern "C" void kernel_launch(void* const* d_in, const int* in_sizes, int n_in,
                              void* d_out, int out_size, void* d_ws, size_t ws_size,
                              hipStream_t stream) {
  const float* feats = (const float*)d_in[0];
  const float* vecs  = (const float*)d_in[1];
  const float* Wh    = (const float*)d_in[2];
  const float* Wcp   = (const float*)d_in[3];
  const float* Wu    = (const float*)d_in[4];
  const float* Wf    = (const float*)d_in[5];
  const float* bfv   = (const float*)d_in[6];
  const float* Wg    = (const float*)d_in[7];
  const float* bg    = (const float*)d_in[8];
  float* out = (float*)d_out;

  char* ws = (char*)d_ws;
  short* sh_ws = (short*)ws;                              // 28,800,000 B
  short* WfT   = (short*)(ws + 28800000);                 // 671,744 B
  short* WgT   = (short*)(ws + 28800000 + 671744);        // 131,072 B
  short* WB1   = (short*)(ws + 28800000 + 671744 + 131072);      // 40,960 B
  short* WuTp  = (short*)(ws + 28800000 + 671744 + 131072 + 40960); // 40,960 B

  // scratch inside dead d_out feats region (written later by gemm_feats):
  short* Vcat = (short*)d_out;                            // [3B][160] bf16 = 96 MB
  float* Vcpf = (float*)((char*)d_out + 96000000);        // [3B][32] f32 = 38.4 MB

  hipLaunchKernelGGL(prep_w,     dim3(1728), dim3(256), 0, stream, Wh, Wcp, Wu, Wf, Wg, WB1, WuTp, WfT, WgT);
  hipLaunchKernelGGL(geo_gemm1,  dim3(1563), dim3(256), 0, stream, vecs, WB1, Vcat, Vcpf);
  hipLaunchKernelGGL(cross_norm, dim3(391),  dim3(256), 0, stream, Vcpf, Vcat, sh_ws);
  hipLaunchKernelGGL(geo_gemm2,  dim3(2344), dim3(256), 0, stream, Vcat, WuTp, out);
  hipLaunchKernelGGL(gemm_feats, dim3(3128), dim3(256), 0, stream, feats, sh_ws, WfT, bfv, out);
  hipLaunchKernelGGL(gemm_gate,  dim3(782),  dim3(256), 0, stream, out, WgT, bg, out);
}

// Round 3
// 728.491 us; speedup vs baseline: 1.8692x; 1.3114x over previous
//
#include <hip/hip_runtime.h>

#define BATCH 100000
#define M3 300000            // 3*BATCH rows
#define VECBASE 51200000     // BATCH*512 floats; start of vectors_out region in d_out
#define KP 704               // gemm_feats padded K (656 -> 11*64)

typedef float fl4  __attribute__((ext_vector_type(4)));
typedef float f32x4 __attribute__((ext_vector_type(4)));
typedef short s16x4 __attribute__((ext_vector_type(4)));
typedef short s16x8 __attribute__((ext_vector_type(8)));

__device__ __forceinline__ short f2bf(float f) {
  unsigned int u = __float_as_uint(f);
  u += 0x7fffu + ((u >> 16) & 1u);
  return (short)(u >> 16);
}
__device__ __forceinline__ float bf2f(short s) {
  return __uint_as_float(((unsigned int)(unsigned short)s) << 16);
}
__device__ __forceinline__ s16x8 pack8(fl4 a, fl4 b) {
  s16x8 o;
  o[0] = f2bf(a[0]); o[1] = f2bf(a[1]); o[2] = f2bf(a[2]); o[3] = f2bf(a[3]);
  o[4] = f2bf(b[0]); o[5] = f2bf(b[1]); o[6] = f2bf(b[2]); o[7] = f2bf(b[3]);
  return o;
}

// ---------------------------------------------------------------------------
// K0: weight prep (bf16 transposes, one-shot)
//  WB1 [160][128], WuTp [128][160], WfT [512][KP=704] (zero-pad k>=656),
//  WgT [128][512]
__global__ __launch_bounds__(256) void prep_w(
    const float* __restrict__ Wh, const float* __restrict__ Wcp,
    const float* __restrict__ Wu, const float* __restrict__ Wf,
    const float* __restrict__ Wg, short* __restrict__ WB1,
    short* __restrict__ WuTp, short* __restrict__ WfT, short* __restrict__ WgT) {
  int gid = blockIdx.x * 256 + threadIdx.x;
  if (gid < 20480) {                       // WB1
    int n = gid >> 7, k = gid & 127;
    WB1[gid] = f2bf(n < 128 ? Wh[k * 128 + n] : Wcp[k * 32 + (n - 128)]);
  } else if (gid < 40960) {                // WuTp
    int i = gid - 20480;
    int o = i / 160, k = i - o * 160;
    WuTp[i] = k < 144 ? f2bf(Wu[k * 128 + o]) : (short)0;
  } else if (gid < 40960 + 512 * KP) {     // WfT
    int i = gid - 40960;
    int n = i / KP, k = i - n * KP;
    WfT[i] = k < 656 ? f2bf(Wf[k * 512 + n]) : (short)0;
  } else if (gid < 40960 + 512 * KP + 65536) {  // WgT
    int i = gid - (40960 + 512 * KP);
    int n = i >> 9, k = i & 511;
    WgT[i] = f2bf(Wg[k * 128 + n]);
  }
}

// ---------------------------------------------------------------------------
// K1: geo GEMM1.  D[3B][160] = A[3B][128] @ WB1^T, A row r=b*3+c, A[r][v]=vecs[b][v][c].
__global__ __launch_bounds__(256) void geo_gemm1(
    const float* __restrict__ vecs, const short* __restrict__ WB1,
    short* __restrict__ Vcat, float* __restrict__ Vcpf) {
  __shared__ short Al[192 * 128];          // row pitch 256B
  const int t = threadIdx.x;
  const int b0 = blockIdx.x * 64;
  const int row0 = blockIdx.x * 192;

#pragma unroll
  for (int it = 0; it < 24; ++it) {
    int fj = (it * 256 + t) * 4;
    int bl = fj / 384;
    int rem = fj - bl * 384;
    int v = rem / 3, c = rem - v * 3;
    fl4 val = (fl4){0.f, 0.f, 0.f, 0.f};
    int b = b0 + bl;
    if (b < BATCH) val = *reinterpret_cast<const fl4*>(&vecs[(size_t)b * 384 + rem]);
#pragma unroll
    for (int e = 0; e < 4; ++e) {
      int row = bl * 3 + c;
      int off = (row << 8) + (v << 1);
      *(short*)((char*)Al + (off ^ ((row & 7) << 4))) = f2bf(val[e]);
      if (++c == 3) { c = 0; ++v; }
    }
  }
  __syncthreads();

  const int lane = t & 63, wv = t >> 6;
  const int wr = wv >> 1, wc = wv & 1;
  const int lr = lane & 15, lk = lane >> 4;
  f32x4 acc[6][5];
#pragma unroll
  for (int i = 0; i < 6; ++i)
#pragma unroll
    for (int j = 0; j < 5; ++j) acc[i][j] = (f32x4){0.f, 0.f, 0.f, 0.f};

#pragma unroll
  for (int kk = 0; kk < 4; ++kk) {
    s16x8 af[6], bq[5];
#pragma unroll
    for (int mi = 0; mi < 6; ++mi) {
      int row = wr * 96 + mi * 16 + lr;
      int off = (row << 8) + (kk << 6) + (lk << 4);
      af[mi] = *(const s16x8*)((const char*)Al + (off ^ ((row & 7) << 4)));
    }
#pragma unroll
    for (int ni = 0; ni < 5; ++ni)
      bq[ni] = *reinterpret_cast<const s16x8*>(
          &WB1[(wc * 80 + ni * 16 + lr) * 128 + (kk << 5) + (lk << 3)]);
#pragma unroll
    for (int mi = 0; mi < 6; ++mi)
#pragma unroll
      for (int ni = 0; ni < 5; ++ni)
        acc[mi][ni] = __builtin_amdgcn_mfma_f32_16x16x32_bf16(af[mi], bq[ni], acc[mi][ni], 0, 0, 0);
  }

#pragma unroll
  for (int mi = 0; mi < 6; ++mi)
#pragma unroll
    for (int ni = 0; ni < 5; ++ni) {
      int col = wc * 80 + ni * 16 + lr;
#pragma unroll
      for (int r = 0; r < 4; ++r) {
        int row = row0 + wr * 96 + mi * 16 + lk * 4 + r;
        if (row < M3) {
          if (col < 128) Vcat[(size_t)row * 160 + col] = f2bf(acc[mi][ni][r]);
          else           Vcpf[(size_t)row * 32 + (col - 128)] = acc[mi][ni][r];
        }
      }
    }
}

// ---------------------------------------------------------------------------
// K2: cross products + clamped norms -> sh bf16.
__global__ __launch_bounds__(256) void cross_norm(
    const float* __restrict__ Vcpf, short* __restrict__ Vcat,
    short* __restrict__ sh_ws) {
  int b = blockIdx.x * 256 + threadIdx.x;
  if (b >= BATCH) return;
  const float* cpf = &Vcpf[(size_t)b * 96];
  short* vr = &Vcat[(size_t)b * 480];
  float cx[16], cy[16], cz[16];
#pragma unroll
  for (int p = 0; p < 16; ++p) {
    float ax = cpf[p],      ay = cpf[32 + p],      az = cpf[64 + p];
    float bx = cpf[16 + p], by = cpf[48 + p],      bz = cpf[80 + p];
    cx[p] = ay * bz - az * by;
    cy[p] = az * bx - ax * bz;
    cz[p] = ax * by - ay * bx;
  }
#pragma unroll
  for (int p = 0; p < 16; ++p) {
    vr[128 + p]       = f2bf(cx[p]);
    vr[160 + 128 + p] = f2bf(cy[p]);
    vr[320 + 128 + p] = f2bf(cz[p]);
    vr[144 + p] = 0; vr[160 + 144 + p] = 0; vr[320 + 144 + p] = 0;
  }
  short* shp = &sh_ws[(size_t)b * 144];
#pragma unroll
  for (int kb = 0; kb < 16; ++kb) {
    s16x8 r0 = *reinterpret_cast<const s16x8*>(&vr[kb * 8]);
    s16x8 r1 = *reinterpret_cast<const s16x8*>(&vr[160 + kb * 8]);
    s16x8 r2 = *reinterpret_cast<const s16x8*>(&vr[320 + kb * 8]);
    s16x8 o;
#pragma unroll
    for (int j = 0; j < 8; ++j) {
      float x = bf2f(r0[j]), y = bf2f(r1[j]), z = bf2f(r2[j]);
      o[j] = f2bf(sqrtf(fmaxf(x * x + y * y + z * z, 1e-8f)));
    }
    *reinterpret_cast<s16x8*>(&shp[kb * 8]) = o;
  }
#pragma unroll
  for (int p = 0; p < 16; ++p)
    shp[128 + p] = f2bf(sqrtf(fmaxf(cx[p] * cx[p] + cy[p] * cy[p] + cz[p] * cz[p], 1e-8f)));
}

// ---------------------------------------------------------------------------
// K3: Vu GEMM.  Vu[3B][128] = Vcat[3B][160] @ WuTp^T; scatter f32 into d_out.
__global__ __launch_bounds__(256) void geo_gemm2(
    const short* __restrict__ Vcat, const short* __restrict__ WuTp,
    float* __restrict__ out) {
  __shared__ short Al[128 * 192];
  const int t = threadIdx.x;
  const int row0 = blockIdx.x << 7;
#pragma unroll
  for (int it = 0; it < 10; ++it) {
    int idx = it * 256 + t;
    int r = idx / 20, ch = idx - r * 20;
    int grow = row0 + r;
    s16x8 q = (s16x8){0, 0, 0, 0, 0, 0, 0, 0};
    if (grow < M3) q = *reinterpret_cast<const s16x8*>(&Vcat[(size_t)grow * 160 + ch * 8]);
    int off = r * 384 + ch * 16;
    *(s16x8*)((char*)Al + (off ^ ((r & 7) << 4))) = q;
  }
  __syncthreads();

  const int lane = t & 63, wv = t >> 6;
  const int wr = wv >> 1, wc = wv & 1;
  const int lr = lane & 15, lk = lane >> 4;
  f32x4 acc[4][4];
#pragma unroll
  for (int i = 0; i < 4; ++i)
#pragma unroll
    for (int j = 0; j < 4; ++j) acc[i][j] = (f32x4){0.f, 0.f, 0.f, 0.f};

#pragma unroll
  for (int kk = 0; kk < 5; ++kk) {
    s16x8 af[4], bq[4];
#pragma unroll
    for (int mi = 0; mi < 4; ++mi) {
      int row = wr * 64 + mi * 16 + lr;
      int off = row * 384 + (kk << 6) + (lk << 4);
      af[mi] = *(const s16x8*)((const char*)Al + (off ^ ((row & 7) << 4)));
    }
#pragma unroll
    for (int ni = 0; ni < 4; ++ni)
      bq[ni] = *reinterpret_cast<const s16x8*>(
          &WuTp[(wc * 64 + ni * 16 + lr) * 160 + (kk << 5) + (lk << 3)]);
#pragma unroll
    for (int mi = 0; mi < 4; ++mi)
#pragma unroll
      for (int ni = 0; ni < 4; ++ni)
        acc[mi][ni] = __builtin_amdgcn_mfma_f32_16x16x32_bf16(af[mi], bq[ni], acc[mi][ni], 0, 0, 0);
  }
#pragma unroll
  for (int mi = 0; mi < 4; ++mi)
#pragma unroll
    for (int ni = 0; ni < 4; ++ni) {
      int col = wc * 64 + ni * 16 + lr;
#pragma unroll
      for (int r = 0; r < 4; ++r) {
        int row = row0 + wr * 64 + mi * 16 + lk * 4 + r;
        if (row < M3) {
          int b = row / 3, c = row - b * 3;
          out[VECBASE + ((size_t)b * 128 + col) * 3 + c] = acc[mi][ni][r];
        }
      }
    }
}

// ---------------------------------------------------------------------------
// K4: feats_out = silu(concat(feats, sh) @ Wf + bf).  M=100000, K=656(->704), N=512.
// BK=64, XOR-swizzled LDS (pitch 128B), register-double-buffered staging,
// XCD-chunked block remap (3128 = 8*391; nt-siblings share an XCD L2).
__global__ __launch_bounds__(256) void gemm_feats(
    const float* __restrict__ feats, const short* __restrict__ sh_ws,
    const short* __restrict__ WfT, const float* __restrict__ bfv,
    float* __restrict__ out) {
  const int bid = blockIdx.x;
  const int swz = (bid & 7) * 391 + (bid >> 3);
  const int mt = swz >> 2, nt = swz & 3;
  const int row0 = mt << 7, n0 = nt << 7;
  const int t = threadIdx.x;
  const int r = t >> 1, h = t & 1;      // staging: thread owns row r, k-half h
  const int grow = row0 + r;
  const bool rowok = grow < BATCH;
  const int lane = t & 63, wv = t >> 6;
  const int wr = wv >> 1, wc = wv & 1;
  const int lr = lane & 15, lk = lane >> 4;

  __shared__ short Al[128 * 64];        // [row][64k] pitch 128B
  __shared__ short Bl[128 * 64];

  f32x4 acc[4][4];
#pragma unroll
  for (int i = 0; i < 4; ++i)
#pragma unroll
    for (int j = 0; j < 4; ++j) acc[i][j] = (f32x4){0.f, 0.f, 0.f, 0.f};
  s16x8 aR[4], bR[4];

  auto loadA = [&](int ks) {
    const int k0 = ks * 64 + h * 32;
    if (k0 < 512) {
      fl4 f[8];
#pragma unroll
      for (int j = 0; j < 8; ++j)
        f[j] = rowok ? *reinterpret_cast<const fl4*>(&feats[(size_t)grow * 512 + k0 + j * 4])
                     : (fl4){0.f, 0.f, 0.f, 0.f};
      aR[0] = pack8(f[0], f[1]); aR[1] = pack8(f[2], f[3]);
      aR[2] = pack8(f[4], f[5]); aR[3] = pack8(f[6], f[7]);
    } else {
#pragma unroll
      for (int c = 0; c < 4; ++c) {
        int kk = k0 + c * 8;
        aR[c] = (rowok && kk < 656)
                    ? *reinterpret_cast<const s16x8*>(&sh_ws[(size_t)grow * 144 + kk - 512])
                    : (s16x8){0, 0, 0, 0, 0, 0, 0, 0};
      }
    }
  };
  auto loadB = [&](int ks) {
    const int k0 = ks * 64 + h * 32;
#pragma unroll
    for (int c = 0; c < 4; ++c)
      bR[c] = *reinterpret_cast<const s16x8*>(&WfT[(size_t)(n0 + r) * KP + k0 + c * 8]);
  };
  auto storeAB = [&]() {
#pragma unroll
    for (int c = 0; c < 4; ++c) {
      int s = h * 4 + c;
      int off = (r << 7) + (((s ^ (r & 7))) << 4);
      *(s16x8*)((char*)Al + off) = aR[c];
      *(s16x8*)((char*)Bl + off) = bR[c];
    }
  };

  loadA(0); loadB(0);
  for (int ks = 0; ks < 11; ++ks) {
    __syncthreads();                 // prior step's readers done
    storeAB();
    __syncthreads();
    if (ks < 10) { loadA(ks + 1); loadB(ks + 1); }   // overlap with MFMA below
#pragma unroll
    for (int kk = 0; kk < 2; ++kk) {
      s16x8 af[4], bq[4];
#pragma unroll
      for (int mi = 0; mi < 4; ++mi) {
        int rw = wr * 64 + mi * 16 + lr;
        int s = kk * 4 + lk;
        af[mi] = *(const s16x8*)((const char*)Al + (rw << 7) + ((s ^ (rw & 7)) << 4));
      }
#pragma unroll
      for (int ni = 0; ni < 4; ++ni) {
        int rw = wc * 64 + ni * 16 + lr;
        int s = kk * 4 + lk;
        bq[ni] = *(const s16x8*)((const char*)Bl + (rw << 7) + ((s ^ (rw & 7)) << 4));
      }
#pragma unroll
      for (int mi = 0; mi < 4; ++mi)
#pragma unroll
        for (int ni = 0; ni < 4; ++ni)
          acc[mi][ni] = __builtin_amdgcn_mfma_f32_16x16x32_bf16(af[mi], bq[ni], acc[mi][ni], 0, 0, 0);
    }
  }
#pragma unroll
  for (int ni = 0; ni < 4; ++ni) {
    int col = n0 + wc * 64 + ni * 16 + lr;
    float bb = bfv[col];
#pragma unroll
    for (int mi = 0; mi < 4; ++mi) {
      int rbase = row0 + wr * 64 + mi * 16 + lk * 4;
#pragma unroll
      for (int rr = 0; rr < 4; ++rr) {
        int gr = rbase + rr;
        if (gr < BATCH) {
          float x = acc[mi][ni][rr] + bb;
          out[(size_t)gr * 512 + col] = x / (1.f + __expf(-x));
        }
      }
    }
  }
}

// ---------------------------------------------------------------------------
// K5: gating GEMM + in-place sigmoid*Vu rescale.  M=100000, K=512, N=128.
// Same BK=64 swizzled/pipelined structure; bijective XCD remap (782 = 8*97+6).
__global__ __launch_bounds__(256) void gemm_gate(
    const float* __restrict__ fo, const short* __restrict__ WgT,
    const float* __restrict__ bg, float* __restrict__ out) {
  const int bid = blockIdx.x;
  const int xcd = bid & 7, idx = bid >> 3;
  const int swz = (xcd < 6 ? xcd * 98 : 6 * 98 + (xcd - 6) * 97) + idx;
  const int row0 = swz << 7;
  const int t = threadIdx.x;
  const int r = t >> 1, h = t & 1;
  const int grow = row0 + r;
  const bool rowok = grow < BATCH;
  const int lane = t & 63, wv = t >> 6;
  const int wr = wv >> 1, wc = wv & 1;
  const int lr = lane & 15, lk = lane >> 4;

  __shared__ short Al[128 * 64];
  __shared__ short Bl[128 * 64];

  f32x4 acc[4][4];
#pragma unroll
  for (int i = 0; i < 4; ++i)
#pragma unroll
    for (int j = 0; j < 4; ++j) acc[i][j] = (f32x4){0.f, 0.f, 0.f, 0.f};
  s16x8 aR[4], bR[4];

  auto loadA = [&](int ks) {
    const int k0 = ks * 64 + h * 32;
    fl4 f[8];
#pragma unroll
    for (int j = 0; j < 8; ++j)
      f[j] = rowok ? *reinterpret_cast<const fl4*>(&fo[(size_t)grow * 512 + k0 + j * 4])
                   : (fl4){0.f, 0.f, 0.f, 0.f};
    aR[0] = pack8(f[0], f[1]); aR[1] = pack8(f[2], f[3]);
    aR[2] = pack8(f[4], f[5]); aR[3] = pack8(f[6], f[7]);
  };
  auto loadB = [&](int ks) {
    const int k0 = ks * 64 + h * 32;
#pragma unroll
    for (int c = 0; c < 4; ++c)
      bR[c] = *reinterpret_cast<const s16x8*>(&WgT[(size_t)r * 512 + k0 + c * 8]);
  };
  auto storeAB = [&]() {
#pragma unroll
    for (int c = 0; c < 4; ++c) {
      int s = h * 4 + c;
      int off = (r << 7) + (((s ^ (r & 7))) << 4);
      *(s16x8*)((char*)Al + off) = aR[c];
      *(s16x8*)((char*)Bl + off) = bR[c];
    }
  };

  loadA(0); loadB(0);
  for (int ks = 0; ks < 8; ++ks) {
    __syncthreads();
    storeAB();
    __syncthreads();
    if (ks < 7) { loadA(ks + 1); loadB(ks + 1); }
#pragma unroll
    for (int kk = 0; kk < 2; ++kk) {
      s16x8 af[4], bq[4];
#pragma unroll
      for (int mi = 0; mi < 4; ++mi) {
        int rw = wr * 64 + mi * 16 + lr;
        int s = kk * 4 + lk;
        af[mi] = *(const s16x8*)((const char*)Al + (rw << 7) + ((s ^ (rw & 7)) << 4));
      }
#pragma unroll
      for (int ni = 0; ni < 4; ++ni) {
        int rw = wc * 64 + ni * 16 + lr;
        int s = kk * 4 + lk;
        bq[ni] = *(const s16x8*)((const char*)Bl + (rw << 7) + ((s ^ (rw & 7)) << 4));
      }
#pragma unroll
      for (int mi = 0; mi < 4; ++mi)
#pragma unroll
        for (int ni = 0; ni < 4; ++ni)
          acc[mi][ni] = __builtin_amdgcn_mfma_f32_16x16x32_bf16(af[mi], bq[ni], acc[mi][ni], 0, 0, 0);
    }
  }
#pragma unroll
  for (int ni = 0; ni < 4; ++ni) {
    int col = wc * 64 + ni * 16 + lr;
    float bb = bg[col];
#pragma unroll
    for (int mi = 0; mi < 4; ++mi) {
      int rbase = row0 + wr * 64 + mi * 16 + lk * 4;
#pragma unroll
      for (int rr = 0; rr < 4; ++rr) {
        int gr = rbase + rr;
        if (gr < BATCH) {
          float x = acc[mi][ni][rr] + bb;
          float gate = 1.f / (1.f + __expf(-x));
          float* pv = &out[VECBASE + ((size_t)gr * 128 + col) * 3];
          pv[0] *= gate; pv[1] *= gate; pv[2] *= gate;
        }
      }
    }
  }
}

// ---------------------------------------------------------------------------
extern "C" void kernel_launch(void* const* d_in, const int* in_sizes, int n_in,
                              void* d_out, int out_size, void* d_ws, size_t ws_size,
                              hipStream_t stream) {
  const float* feats = (const float*)d_in[0];
  const float* vecs  = (const float*)d_in[1];
  const float* Wh    = (const float*)d_in[2];
  const float* Wcp   = (const float*)d_in[3];
  const float* Wu    = (const float*)d_in[4];
  const float* Wf    = (const float*)d_in[5];
  const float* bfv   = (const float*)d_in[6];
  const float* Wg    = (const float*)d_in[7];
  const float* bg    = (const float*)d_in[8];
  float* out = (float*)d_out;

  char* ws = (char*)d_ws;
  short* sh_ws = (short*)ws;                               // 28,800,000 B
  short* WfT   = (short*)(ws + 28800000);                  // 512*704*2 = 720,896 B
  short* WgT   = (short*)(ws + 28800000 + 720896);         // 131,072 B
  short* WB1   = (short*)(ws + 28800000 + 720896 + 131072);           // 40,960 B
  short* WuTp  = (short*)(ws + 28800000 + 720896 + 131072 + 40960);   // 40,960 B

  // scratch inside dead d_out feats region (overwritten later by gemm_feats):
  short* Vcat = (short*)d_out;                             // [3B][160] bf16 = 96 MB
  float* Vcpf = (float*)((char*)d_out + 96000000);         // [3B][32] f32 = 38.4 MB

  hipLaunchKernelGGL(prep_w,     dim3(1824), dim3(256), 0, stream, Wh, Wcp, Wu, Wf, Wg, WB1, WuTp, WfT, WgT);
  hipLaunchKernelGGL(geo_gemm1,  dim3(1563), dim3(256), 0, stream, vecs, WB1, Vcat, Vcpf);
  hipLaunchKernelGGL(cross_norm, dim3(391),  dim3(256), 0, stream, Vcpf, Vcat, sh_ws);
  hipLaunchKernelGGL(geo_gemm2,  dim3(2344), dim3(256), 0, stream, Vcat, WuTp, out);
  hipLaunchKernelGGL(gemm_feats, dim3(3128), dim3(256), 0, stream, feats, sh_ws, WfT, bfv, out);
  hipLaunchKernelGGL(gemm_gate,  dim3(782),  dim3(256), 0, stream, out, WgT, bg, out);
}

// Round 4
// 534.915 us; speedup vs baseline: 2.5456x; 1.3619x over previous
//
#include <hip/hip_runtime.h>

#define BATCH 100000
#define M3 300000            // 3*BATCH rows
#define VECBASE 51200000     // BATCH*512 floats; start of vectors_out region in d_out
#define KP 704               // gemm_feats padded K (656 -> 22*32)

typedef float fl4  __attribute__((ext_vector_type(4)));
typedef float f32x4 __attribute__((ext_vector_type(4)));
typedef short s16x8 __attribute__((ext_vector_type(8)));

__device__ __forceinline__ short f2bf(float f) {
  unsigned int u = __float_as_uint(f);
  u += 0x7fffu + ((u >> 16) & 1u);
  return (short)(u >> 16);
}
__device__ __forceinline__ float bf2f(short s) {
  return __uint_as_float(((unsigned int)(unsigned short)s) << 16);
}
__device__ __forceinline__ s16x8 pack8(fl4 a, fl4 b) {
  s16x8 o;
  o[0] = f2bf(a[0]); o[1] = f2bf(a[1]); o[2] = f2bf(a[2]); o[3] = f2bf(a[3]);
  o[4] = f2bf(b[0]); o[5] = f2bf(b[1]); o[6] = f2bf(b[2]); o[7] = f2bf(b[3]);
  return o;
}
__device__ __forceinline__ void glds16(const void* g, void* l) {
  __builtin_amdgcn_global_load_lds((const __attribute__((address_space(1))) void*)g,
                                   (__attribute__((address_space(3))) void*)l, 16, 0, 0);
}

// ---------------------------------------------------------------------------
// K0: weight prep (bf16 transposes, one-shot)
__global__ __launch_bounds__(256) void prep_w(
    const float* __restrict__ Wh, const float* __restrict__ Wcp,
    const float* __restrict__ Wu, const float* __restrict__ Wf,
    const float* __restrict__ Wg, short* __restrict__ WB1,
    short* __restrict__ WuTp, short* __restrict__ WfT, short* __restrict__ WgT) {
  int gid = blockIdx.x * 256 + threadIdx.x;
  if (gid < 20480) {                       // WB1 [160][128]
    int n = gid >> 7, k = gid & 127;
    WB1[gid] = f2bf(n < 128 ? Wh[k * 128 + n] : Wcp[k * 32 + (n - 128)]);
  } else if (gid < 40960) {                // WuTp [128][160]
    int i = gid - 20480;
    int o = i / 160, k = i - o * 160;
    WuTp[i] = k < 144 ? f2bf(Wu[k * 128 + o]) : (short)0;
  } else if (gid < 40960 + 512 * KP) {     // WfT [512][704]
    int i = gid - 40960;
    int n = i / KP, k = i - n * KP;
    WfT[i] = k < 656 ? f2bf(Wf[k * 512 + n]) : (short)0;
  } else if (gid < 40960 + 512 * KP + 65536) {  // WgT [128][512]
    int i = gid - (40960 + 512 * KP);
    int n = i >> 9, k = i & 511;
    WgT[i] = f2bf(Wg[k * 128 + n]);
  }
}

// ---------------------------------------------------------------------------
// K1: fused geo GEMM1 + cross + norms.
// D[192][160] = A[192][128] @ WB1^T per block (64 complete b's), then in-LDS:
// cross(Vcp[:16],Vcp[16:]) -> cols 128..143 (144..159 zero), sh -> sh192 bf16
// (cols 144..191 zero-padded), Vcat [row][160] bf16 -> d_out scratch.
__global__ __launch_bounds__(256) void geo_gemm1(
    const float* __restrict__ vecs, const short* __restrict__ WB1,
    short* __restrict__ Vcat, short* __restrict__ sh192) {
  __shared__ __align__(16) short U[192 * 160];   // 61,440 B
  const int t = threadIdx.x;
  const int b0 = blockIdx.x * 64;
  const int row0 = blockIdx.x * 192;

  // stage A [192][128] bf16 (pitch 256B, XOR swizzle) into first 48KB of U
#pragma unroll
  for (int it = 0; it < 24; ++it) {
    int fj = (it * 256 + t) * 4;
    int bl = fj / 384;
    int rem = fj - bl * 384;
    int v = rem / 3, c = rem - v * 3;
    fl4 val = (fl4){0.f, 0.f, 0.f, 0.f};
    int b = b0 + bl;
    if (b < BATCH) val = *reinterpret_cast<const fl4*>(&vecs[(size_t)b * 384 + rem]);
#pragma unroll
    for (int e = 0; e < 4; ++e) {
      int row = bl * 3 + c;
      int off = (row << 8) + (v << 1);
      *(short*)((char*)U + (off ^ ((row & 7) << 4))) = f2bf(val[e]);
      if (++c == 3) { c = 0; ++v; }
    }
  }
  __syncthreads();

  const int lane = t & 63, wv = t >> 6;
  const int wr = wv >> 1, wc = wv & 1;
  const int lr = lane & 15, lk = lane >> 4;
  f32x4 acc[6][5];
#pragma unroll
  for (int i = 0; i < 6; ++i)
#pragma unroll
    for (int j = 0; j < 5; ++j) acc[i][j] = (f32x4){0.f, 0.f, 0.f, 0.f};

#pragma unroll
  for (int kk = 0; kk < 4; ++kk) {
    s16x8 af[6], bq[5];
#pragma unroll
    for (int mi = 0; mi < 6; ++mi) {
      int row = wr * 96 + mi * 16 + lr;
      int off = (row << 8) + (kk << 6) + (lk << 4);
      af[mi] = *(const s16x8*)((const char*)U + (off ^ ((row & 7) << 4)));
    }
#pragma unroll
    for (int ni = 0; ni < 5; ++ni)
      bq[ni] = *reinterpret_cast<const s16x8*>(
          &WB1[(wc * 80 + ni * 16 + lr) * 128 + (kk << 5) + (lk << 3)]);
#pragma unroll
    for (int mi = 0; mi < 6; ++mi)
#pragma unroll
      for (int ni = 0; ni < 5; ++ni)
        acc[mi][ni] = __builtin_amdgcn_mfma_f32_16x16x32_bf16(af[mi], bq[ni], acc[mi][ni], 0, 0, 0);
  }
  __syncthreads();   // staging reads done; reuse U as result [192][160] bf16

#pragma unroll
  for (int mi = 0; mi < 6; ++mi)
#pragma unroll
    for (int ni = 0; ni < 5; ++ni) {
      int col = wc * 80 + ni * 16 + lr;
#pragma unroll
      for (int r = 0; r < 4; ++r) {
        int row = wr * 96 + mi * 16 + lk * 4 + r;
        U[row * 160 + col] = f2bf(acc[mi][ni][r]);
      }
    }
  __syncthreads();

  // cross phase: 4 threads per b, each owns 4 p's (cols 128+p / 144+p fully owned)
  {
    int bl = t >> 2, pj = t & 3;
    int gb = b0 + bl;
    float shcp[4];
#pragma unroll
    for (int q = 0; q < 4; ++q) {
      int p = pj * 4 + q;
      float ax = bf2f(U[(bl * 3 + 0) * 160 + 128 + p]);
      float ay = bf2f(U[(bl * 3 + 1) * 160 + 128 + p]);
      float az = bf2f(U[(bl * 3 + 2) * 160 + 128 + p]);
      float bx = bf2f(U[(bl * 3 + 0) * 160 + 144 + p]);
      float by = bf2f(U[(bl * 3 + 1) * 160 + 144 + p]);
      float bz = bf2f(U[(bl * 3 + 2) * 160 + 144 + p]);
      float cx = ay * bz - az * by;
      float cy = az * bx - ax * bz;
      float cz = ax * by - ay * bx;
      U[(bl * 3 + 0) * 160 + 128 + p] = f2bf(cx);
      U[(bl * 3 + 1) * 160 + 128 + p] = f2bf(cy);
      U[(bl * 3 + 2) * 160 + 128 + p] = f2bf(cz);
      U[(bl * 3 + 0) * 160 + 144 + p] = 0;
      U[(bl * 3 + 1) * 160 + 144 + p] = 0;
      U[(bl * 3 + 2) * 160 + 144 + p] = 0;
      shcp[q] = sqrtf(fmaxf(cx * cx + cy * cy + cz * cz, 1e-8f));
    }
    if (gb < BATCH) {
#pragma unroll
      for (int q = 0; q < 4; ++q) sh192[(size_t)gb * 192 + 128 + pj * 4 + q] = f2bf(shcp[q]);
#pragma unroll
      for (int z = 0; z < 12; ++z) sh192[(size_t)gb * 192 + 144 + pj * 12 + z] = 0;
    }
  }
  // norm phase (k<128): disjoint cols from cross phase -> no extra barrier
  {
    int bl = t >> 2, kq = t & 3;
    int gb = b0 + bl;
    if (gb < BATCH) {
#pragma unroll
      for (int j = 0; j < 4; ++j) {
        int k = kq * 32 + j * 8;
        s16x8 r0 = *(const s16x8*)&U[(bl * 3 + 0) * 160 + k];
        s16x8 r1 = *(const s16x8*)&U[(bl * 3 + 1) * 160 + k];
        s16x8 r2 = *(const s16x8*)&U[(bl * 3 + 2) * 160 + k];
        s16x8 o;
#pragma unroll
        for (int e = 0; e < 8; ++e) {
          float x = bf2f(r0[e]), y = bf2f(r1[e]), z = bf2f(r2[e]);
          o[e] = f2bf(sqrtf(fmaxf(x * x + y * y + z * z, 1e-8f)));
        }
        *(s16x8*)&sh192[(size_t)gb * 192 + k] = o;
      }
    }
  }
  __syncthreads();   // cross writes to U done before bulk copy
  {
    const char* src = (const char*)U;
    char* dst = (char*)Vcat + (size_t)row0 * 320;
    size_t lim = 96000000ULL - (size_t)row0 * 320;
#pragma unroll
    for (int j = 0; j < 15; ++j) {
      int byte = (j * 256 + t) * 16;
      if ((size_t)byte < lim)
        *(s16x8*)(dst + byte) = *(const s16x8*)(src + byte);
    }
  }
}

// ---------------------------------------------------------------------------
// K2: Vu GEMM.  Vub[3B][128] bf16 = Vcat[3B][160] @ WuTp^T.
__global__ __launch_bounds__(256) void geo_gemm2(
    const short* __restrict__ Vcat, const short* __restrict__ WuTp,
    short* __restrict__ Vub) {
  __shared__ __align__(16) short Al[128 * 192];
  const int t = threadIdx.x;
  const int row0 = blockIdx.x << 7;
#pragma unroll
  for (int it = 0; it < 10; ++it) {
    int idx = it * 256 + t;
    int r = idx / 20, ch = idx - r * 20;
    int grow = row0 + r;
    s16x8 q = (s16x8){0, 0, 0, 0, 0, 0, 0, 0};
    if (grow < M3) q = *reinterpret_cast<const s16x8*>(&Vcat[(size_t)grow * 160 + ch * 8]);
    int off = r * 384 + ch * 16;
    *(s16x8*)((char*)Al + (off ^ ((r & 7) << 4))) = q;
  }
  __syncthreads();

  const int lane = t & 63, wv = t >> 6;
  const int wr = wv >> 1, wc = wv & 1;
  const int lr = lane & 15, lk = lane >> 4;
  f32x4 acc[4][4];
#pragma unroll
  for (int i = 0; i < 4; ++i)
#pragma unroll
    for (int j = 0; j < 4; ++j) acc[i][j] = (f32x4){0.f, 0.f, 0.f, 0.f};

#pragma unroll
  for (int kk = 0; kk < 5; ++kk) {
    s16x8 af[4], bq[4];
#pragma unroll
    for (int mi = 0; mi < 4; ++mi) {
      int row = wr * 64 + mi * 16 + lr;
      int off = row * 384 + (kk << 6) + (lk << 4);
      af[mi] = *(const s16x8*)((const char*)Al + (off ^ ((row & 7) << 4)));
    }
#pragma unroll
    for (int ni = 0; ni < 4; ++ni)
      bq[ni] = *reinterpret_cast<const s16x8*>(
          &WuTp[(wc * 64 + ni * 16 + lr) * 160 + (kk << 5) + (lk << 3)]);
#pragma unroll
    for (int mi = 0; mi < 4; ++mi)
#pragma unroll
      for (int ni = 0; ni < 4; ++ni)
        acc[mi][ni] = __builtin_amdgcn_mfma_f32_16x16x32_bf16(af[mi], bq[ni], acc[mi][ni], 0, 0, 0);
  }
#pragma unroll
  for (int mi = 0; mi < 4; ++mi)
#pragma unroll
    for (int ni = 0; ni < 4; ++ni) {
      int col = wc * 64 + ni * 16 + lr;
#pragma unroll
      for (int r = 0; r < 4; ++r) {
        int row = row0 + wr * 64 + mi * 16 + lk * 4 + r;
        if (row < M3) Vub[(size_t)row * 128 + col] = f2bf(acc[mi][ni][r]);
      }
    }
}

// ---------------------------------------------------------------------------
// K3: feats_out = silu(concat(feats, sh) @ Wf + bf).  M=100000, K=656(->704), N=512.
// BK=32, B via global_load_lds (source-XOR swizzled), A reg-staged with 1-step
// register prefetch issued after the barrier (overlaps MFMA phase).
__global__ __launch_bounds__(256) void gemm_feats(
    const float* __restrict__ feats, const short* __restrict__ sh192,
    const short* __restrict__ WfT, const float* __restrict__ bfv,
    float* __restrict__ out) {
  const int bid = blockIdx.x;
  const int swz = (bid & 7) * 391 + (bid >> 3);
  const int mt = swz >> 2, nt = swz & 3;
  const int row0 = mt << 7, n0 = nt << 7;
  const int t = threadIdx.x;
  const int lane = t & 63, wv = t >> 6;
  const int wr = wv >> 1, wc = wv & 1;
  const int lr = lane & 15, lk = lane >> 4;

  __shared__ __align__(16) short Al[128 * 40];   // pitch 80 B (2-way, free)
  __shared__ __align__(16) short Bl[128 * 32];   // pitch 64 B, chunk-XOR layout

  const int ar = t >> 1, h = t & 1;              // A staging: row ar, k-half h
  const size_t arowc = (size_t)min(row0 + ar, BATCH - 1);
  const float* aFp = &feats[arowc * 512 + h * 16];
  const short* aSp = &sh192[arowc * 192 + h * 16];

  const int seg0 = wv * 2;                        // B glds: wave stages 2 segs
  const int r16 = lane >> 2, ch = lane & 3;

  f32x4 acc[4][4];
#pragma unroll
  for (int i = 0; i < 4; ++i)
#pragma unroll
    for (int j = 0; j < 4; ++j) acc[i][j] = (f32x4){0.f, 0.f, 0.f, 0.f};
  fl4 fR[4];
  s16x8 sR0, sR1;

  auto loadA = [&](int ks) {
    const int k0 = ks << 5;
    if (k0 < 512) {
#pragma unroll
      for (int j = 0; j < 4; ++j) fR[j] = *reinterpret_cast<const fl4*>(aFp + k0 + j * 4);
    } else {
      sR0 = *reinterpret_cast<const s16x8*>(aSp + (k0 - 512));
      sR1 = *reinterpret_cast<const s16x8*>(aSp + (k0 - 512) + 8);
    }
  };
  auto storeA = [&](int ks) {
    s16x8 lo, hi;
    if ((ks << 5) < 512) { lo = pack8(fR[0], fR[1]); hi = pack8(fR[2], fR[3]); }
    else { lo = sR0; hi = sR1; }
    *(s16x8*)&Al[ar * 40 + h * 16] = lo;
    *(s16x8*)&Al[ar * 40 + h * 16 + 8] = hi;
  };
  auto gldsB = [&](int ks) {
    const int k0 = ks << 5;
#pragma unroll
    for (int i = 0; i < 2; ++i) {
      int seg = seg0 + i;
      int nrow = seg * 16 + r16;
      const char* src = (const char*)WfT + (size_t)(n0 + nrow) * (KP * 2) +
                        (size_t)k0 * 2 + ((ch ^ (nrow & 3)) << 4);
      glds16(src, &Bl[seg * 512]);
    }
  };

  loadA(0);
  for (int ks = 0; ks < 22; ++ks) {
    if (ks) __syncthreads();
    storeA(ks);
    gldsB(ks);
    __syncthreads();
    if (ks + 1 < 22) loadA(ks + 1);
    s16x8 af[4], bq[4];
#pragma unroll
    for (int mi = 0; mi < 4; ++mi) {
      int rw = wr * 64 + mi * 16 + lr;
      af[mi] = *(const s16x8*)&Al[rw * 40 + lk * 8];
    }
#pragma unroll
    for (int ni = 0; ni < 4; ++ni) {
      int rw = wc * 64 + ni * 16 + lr;
      bq[ni] = *(const s16x8*)&Bl[rw * 32 + ((lk ^ (rw & 3)) << 3)];
    }
#pragma unroll
    for (int mi = 0; mi < 4; ++mi)
#pragma unroll
      for (int ni = 0; ni < 4; ++ni)
        acc[mi][ni] = __builtin_amdgcn_mfma_f32_16x16x32_bf16(af[mi], bq[ni], acc[mi][ni], 0, 0, 0);
  }
#pragma unroll
  for (int ni = 0; ni < 4; ++ni) {
    int col = n0 + wc * 64 + ni * 16 + lr;
    float bb = bfv[col];
#pragma unroll
    for (int mi = 0; mi < 4; ++mi) {
      int rbase = row0 + wr * 64 + mi * 16 + lk * 4;
#pragma unroll
      for (int rr = 0; rr < 4; ++rr) {
        int gr = rbase + rr;
        if (gr < BATCH) {
          float x = acc[mi][ni][rr] + bb;
          out[(size_t)gr * 512 + col] = x / (1.f + __expf(-x));
        }
      }
    }
  }
}

// ---------------------------------------------------------------------------
// K4: gating GEMM + sigmoid*Vub -> vectors_out f32.  M=100000, K=512, N=128.
__global__ __launch_bounds__(256) void gemm_gate(
    const float* __restrict__ fo, const short* __restrict__ WgT,
    const float* __restrict__ bg, const short* __restrict__ Vub,
    float* __restrict__ out) {
  const int bid = blockIdx.x;
  const int xcd = bid & 7, bidx = bid >> 3;
  const int swz = (xcd < 6 ? xcd * 98 : 6 * 98 + (xcd - 6) * 97) + bidx;
  const int row0 = swz << 7;
  const int t = threadIdx.x;
  const int lane = t & 63, wv = t >> 6;
  const int wr = wv >> 1, wc = wv & 1;
  const int lr = lane & 15, lk = lane >> 4;

  __shared__ __align__(16) short Al[128 * 40];
  __shared__ __align__(16) short Bl[128 * 32];

  const int ar = t >> 1, h = t & 1;
  const size_t arowc = (size_t)min(row0 + ar, BATCH - 1);
  const float* aFp = &fo[arowc * 512 + h * 16];
  const int seg0 = wv * 2;
  const int r16 = lane >> 2, ch = lane & 3;

  f32x4 acc[4][4];
#pragma unroll
  for (int i = 0; i < 4; ++i)
#pragma unroll
    for (int j = 0; j < 4; ++j) acc[i][j] = (f32x4){0.f, 0.f, 0.f, 0.f};
  fl4 fR[4];

  auto loadA = [&](int ks) {
    const int k0 = ks << 5;
#pragma unroll
    for (int j = 0; j < 4; ++j) fR[j] = *reinterpret_cast<const fl4*>(aFp + k0 + j * 4);
  };
  auto gldsB = [&](int ks) {
    const int k0 = ks << 5;
#pragma unroll
    for (int i = 0; i < 2; ++i) {
      int seg = seg0 + i;
      int nrow = seg * 16 + r16;
      const char* src = (const char*)WgT + (size_t)nrow * 1024 +
                        (size_t)k0 * 2 + ((ch ^ (nrow & 3)) << 4);
      glds16(src, &Bl[seg * 512]);
    }
  };

  loadA(0);
  for (int ks = 0; ks < 16; ++ks) {
    if (ks) __syncthreads();
    {
      s16x8 lo = pack8(fR[0], fR[1]), hi = pack8(fR[2], fR[3]);
      *(s16x8*)&Al[ar * 40 + h * 16] = lo;
      *(s16x8*)&Al[ar * 40 + h * 16 + 8] = hi;
    }
    gldsB(ks);
    __syncthreads();
    if (ks + 1 < 16) loadA(ks + 1);
    s16x8 af[4], bq[4];
#pragma unroll
    for (int mi = 0; mi < 4; ++mi) {
      int rw = wr * 64 + mi * 16 + lr;
      af[mi] = *(const s16x8*)&Al[rw * 40 + lk * 8];
    }
#pragma unroll
    for (int ni = 0; ni < 4; ++ni) {
      int rw = wc * 64 + ni * 16 + lr;
      bq[ni] = *(const s16x8*)&Bl[rw * 32 + ((lk ^ (rw & 3)) << 3)];
    }
#pragma unroll
    for (int mi = 0; mi < 4; ++mi)
#pragma unroll
      for (int ni = 0; ni < 4; ++ni)
        acc[mi][ni] = __builtin_amdgcn_mfma_f32_16x16x32_bf16(af[mi], bq[ni], acc[mi][ni], 0, 0, 0);
  }
#pragma unroll
  for (int ni = 0; ni < 4; ++ni) {
    int col = wc * 64 + ni * 16 + lr;
    float bb = bg[col];
#pragma unroll
    for (int mi = 0; mi < 4; ++mi) {
      int rbase = row0 + wr * 64 + mi * 16 + lk * 4;
#pragma unroll
      for (int rr = 0; rr < 4; ++rr) {
        int gr = rbase + rr;
        if (gr < BATCH) {
          float x = acc[mi][ni][rr] + bb;
          float gate = 1.f / (1.f + __expf(-x));
          size_t vb = (size_t)(3 * gr) * 128 + col;
          float* po = &out[VECBASE + ((size_t)gr * 128 + col) * 3];
          po[0] = gate * bf2f(Vub[vb]);
          po[1] = gate * bf2f(Vub[vb + 128]);
          po[2] = gate * bf2f(Vub[vb + 256]);
        }
      }
    }
  }
}

// ---------------------------------------------------------------------------
extern "C" void kernel_launch(void* const* d_in, const int* in_sizes, int n_in,
                              void* d_out, int out_size, void* d_ws, size_t ws_size,
                              hipStream_t stream) {
  const float* feats = (const float*)d_in[0];
  const float* vecs  = (const float*)d_in[1];
  const float* Wh    = (const float*)d_in[2];
  const float* Wcp   = (const float*)d_in[3];
  const float* Wu    = (const float*)d_in[4];
  const float* Wf    = (const float*)d_in[5];
  const float* bfv   = (const float*)d_in[6];
  const float* Wg    = (const float*)d_in[7];
  const float* bg    = (const float*)d_in[8];
  float* out = (float*)d_out;

  char* ws = (char*)d_ws;
  short* sh192 = (short*)ws;                               // 100000*192*2 = 38,400,000
  short* Vub   = (short*)(ws + 38400000);                  // 300000*128*2 = 76,800,000
  short* WfT   = (short*)(ws + 115200000);                 // 512*704*2    =    720,896
  short* WgT   = (short*)(ws + 115920896);                 // 128*512*2    =    131,072
  short* WB1   = (short*)(ws + 116051968);                 //                   40,960
  short* WuTp  = (short*)(ws + 116092928);                 //                   40,960

  // Vcat scratch in dead d_out feats region (consumed by geo_gemm2 before
  // gemm_feats overwrites the region): [3B][160] bf16 = 96,000,000 B
  short* Vcat = (short*)d_out;

  hipLaunchKernelGGL(prep_w,     dim3(1824), dim3(256), 0, stream, Wh, Wcp, Wu, Wf, Wg, WB1, WuTp, WfT, WgT);
  hipLaunchKernelGGL(geo_gemm1,  dim3(1563), dim3(256), 0, stream, vecs, WB1, Vcat, sh192);
  hipLaunchKernelGGL(geo_gemm2,  dim3(2344), dim3(256), 0, stream, Vcat, WuTp, Vub);
  hipLaunchKernelGGL(gemm_feats, dim3(3128), dim3(256), 0, stream, feats, sh192, WfT, bfv, out);
  hipLaunchKernelGGL(gemm_gate,  dim3(782),  dim3(256), 0, stream, out, WgT, bg, Vub, out);
}

// Round 5
// 523.554 us; speedup vs baseline: 2.6008x; 1.0217x over previous
//
#include <hip/hip_runtime.h>

#define BATCH 100000
#define M3 300000            // 3*BATCH rows
#define VECBASE 51200000     // BATCH*512 floats; start of vectors_out region in d_out
#define KP 704               // gemm_feats padded K (656 -> 22*32)

typedef float fl4  __attribute__((ext_vector_type(4)));
typedef float f32x4 __attribute__((ext_vector_type(4)));
typedef short s16x8 __attribute__((ext_vector_type(8)));

__device__ __forceinline__ short f2bf(float f) {
  unsigned int u = __float_as_uint(f);
  u += 0x7fffu + ((u >> 16) & 1u);
  return (short)(u >> 16);
}
__device__ __forceinline__ float bf2f(short s) {
  return __uint_as_float(((unsigned int)(unsigned short)s) << 16);
}
__device__ __forceinline__ s16x8 pack8(fl4 a, fl4 b) {
  s16x8 o;
  o[0] = f2bf(a[0]); o[1] = f2bf(a[1]); o[2] = f2bf(a[2]); o[3] = f2bf(a[3]);
  o[4] = f2bf(b[0]); o[5] = f2bf(b[1]); o[6] = f2bf(b[2]); o[7] = f2bf(b[3]);
  return o;
}
__device__ __forceinline__ void glds16(const void* g, void* l) {
  __builtin_amdgcn_global_load_lds((const __attribute__((address_space(1))) void*)g,
                                   (__attribute__((address_space(3))) void*)l, 16, 0, 0);
}
// swizzled chunk offset within a 64-B (32-short) row: chunk ck stored at ck^((row>>1)&3)
#define SWOFF(row, ck) (((row) << 5) + ((((ck) ^ (((row) >> 1) & 3))) << 3))

// ---------------------------------------------------------------------------
// K0: weight prep (bf16 transposes, one-shot)
__global__ __launch_bounds__(256) void prep_w(
    const float* __restrict__ Wh, const float* __restrict__ Wcp,
    const float* __restrict__ Wu, const float* __restrict__ Wf,
    const float* __restrict__ Wg, short* __restrict__ WB1,
    short* __restrict__ WuTp, short* __restrict__ WfT, short* __restrict__ WgT) {
  int gid = blockIdx.x * 256 + threadIdx.x;
  if (gid < 20480) {                       // WB1 [160][128]
    int n = gid >> 7, k = gid & 127;
    WB1[gid] = f2bf(n < 128 ? Wh[k * 128 + n] : Wcp[k * 32 + (n - 128)]);
  } else if (gid < 40960) {                // WuTp [128][160]
    int i = gid - 20480;
    int o = i / 160, k = i - o * 160;
    WuTp[i] = k < 144 ? f2bf(Wu[k * 128 + o]) : (short)0;
  } else if (gid < 40960 + 512 * KP) {     // WfT [512][704]
    int i = gid - 40960;
    int n = i / KP, k = i - n * KP;
    WfT[i] = k < 656 ? f2bf(Wf[k * 512 + n]) : (short)0;
  } else if (gid < 40960 + 512 * KP + 65536) {  // WgT [128][512]
    int i = gid - (40960 + 512 * KP);
    int n = i >> 9, k = i & 511;
    WgT[i] = f2bf(Wg[k * 128 + n]);
  }
}

// ---------------------------------------------------------------------------
// K1: fused geo GEMM1 + cross + norms. (unchanged from R4)
__global__ __launch_bounds__(256) void geo_gemm1(
    const float* __restrict__ vecs, const short* __restrict__ WB1,
    short* __restrict__ Vcat, short* __restrict__ sh192) {
  __shared__ __align__(16) short U[192 * 160];
  const int t = threadIdx.x;
  const int b0 = blockIdx.x * 64;
  const int row0 = blockIdx.x * 192;

#pragma unroll
  for (int it = 0; it < 24; ++it) {
    int fj = (it * 256 + t) * 4;
    int bl = fj / 384;
    int rem = fj - bl * 384;
    int v = rem / 3, c = rem - v * 3;
    fl4 val = (fl4){0.f, 0.f, 0.f, 0.f};
    int b = b0 + bl;
    if (b < BATCH) val = *reinterpret_cast<const fl4*>(&vecs[(size_t)b * 384 + rem]);
#pragma unroll
    for (int e = 0; e < 4; ++e) {
      int row = bl * 3 + c;
      int off = (row << 8) + (v << 1);
      *(short*)((char*)U + (off ^ ((row & 7) << 4))) = f2bf(val[e]);
      if (++c == 3) { c = 0; ++v; }
    }
  }
  __syncthreads();

  const int lane = t & 63, wv = t >> 6;
  const int wr = wv >> 1, wc = wv & 1;
  const int lr = lane & 15, lk = lane >> 4;
  f32x4 acc[6][5];
#pragma unroll
  for (int i = 0; i < 6; ++i)
#pragma unroll
    for (int j = 0; j < 5; ++j) acc[i][j] = (f32x4){0.f, 0.f, 0.f, 0.f};

#pragma unroll
  for (int kk = 0; kk < 4; ++kk) {
    s16x8 af[6], bq[5];
#pragma unroll
    for (int mi = 0; mi < 6; ++mi) {
      int row = wr * 96 + mi * 16 + lr;
      int off = (row << 8) + (kk << 6) + (lk << 4);
      af[mi] = *(const s16x8*)((const char*)U + (off ^ ((row & 7) << 4)));
    }
#pragma unroll
    for (int ni = 0; ni < 5; ++ni)
      bq[ni] = *reinterpret_cast<const s16x8*>(
          &WB1[(wc * 80 + ni * 16 + lr) * 128 + (kk << 5) + (lk << 3)]);
#pragma unroll
    for (int mi = 0; mi < 6; ++mi)
#pragma unroll
      for (int ni = 0; ni < 5; ++ni)
        acc[mi][ni] = __builtin_amdgcn_mfma_f32_16x16x32_bf16(af[mi], bq[ni], acc[mi][ni], 0, 0, 0);
  }
  __syncthreads();

#pragma unroll
  for (int mi = 0; mi < 6; ++mi)
#pragma unroll
    for (int ni = 0; ni < 5; ++ni) {
      int col = wc * 80 + ni * 16 + lr;
#pragma unroll
      for (int r = 0; r < 4; ++r) {
        int row = wr * 96 + mi * 16 + lk * 4 + r;
        U[row * 160 + col] = f2bf(acc[mi][ni][r]);
      }
    }
  __syncthreads();

  {
    int bl = t >> 2, pj = t & 3;
    int gb = b0 + bl;
    float shcp[4];
#pragma unroll
    for (int q = 0; q < 4; ++q) {
      int p = pj * 4 + q;
      float ax = bf2f(U[(bl * 3 + 0) * 160 + 128 + p]);
      float ay = bf2f(U[(bl * 3 + 1) * 160 + 128 + p]);
      float az = bf2f(U[(bl * 3 + 2) * 160 + 128 + p]);
      float bx = bf2f(U[(bl * 3 + 0) * 160 + 144 + p]);
      float by = bf2f(U[(bl * 3 + 1) * 160 + 144 + p]);
      float bz = bf2f(U[(bl * 3 + 2) * 160 + 144 + p]);
      float cx = ay * bz - az * by;
      float cy = az * bx - ax * bz;
      float cz = ax * by - ay * bx;
      U[(bl * 3 + 0) * 160 + 128 + p] = f2bf(cx);
      U[(bl * 3 + 1) * 160 + 128 + p] = f2bf(cy);
      U[(bl * 3 + 2) * 160 + 128 + p] = f2bf(cz);
      U[(bl * 3 + 0) * 160 + 144 + p] = 0;
      U[(bl * 3 + 1) * 160 + 144 + p] = 0;
      U[(bl * 3 + 2) * 160 + 144 + p] = 0;
      shcp[q] = sqrtf(fmaxf(cx * cx + cy * cy + cz * cz, 1e-8f));
    }
    if (gb < BATCH) {
#pragma unroll
      for (int q = 0; q < 4; ++q) sh192[(size_t)gb * 192 + 128 + pj * 4 + q] = f2bf(shcp[q]);
#pragma unroll
      for (int z = 0; z < 12; ++z) sh192[(size_t)gb * 192 + 144 + pj * 12 + z] = 0;
    }
  }
  {
    int bl = t >> 2, kq = t & 3;
    int gb = b0 + bl;
    if (gb < BATCH) {
#pragma unroll
      for (int j = 0; j < 4; ++j) {
        int k = kq * 32 + j * 8;
        s16x8 r0 = *(const s16x8*)&U[(bl * 3 + 0) * 160 + k];
        s16x8 r1 = *(const s16x8*)&U[(bl * 3 + 1) * 160 + k];
        s16x8 r2 = *(const s16x8*)&U[(bl * 3 + 2) * 160 + k];
        s16x8 o;
#pragma unroll
        for (int e = 0; e < 8; ++e) {
          float x = bf2f(r0[e]), y = bf2f(r1[e]), z = bf2f(r2[e]);
          o[e] = f2bf(sqrtf(fmaxf(x * x + y * y + z * z, 1e-8f)));
        }
        *(s16x8*)&sh192[(size_t)gb * 192 + k] = o;
      }
    }
  }
  __syncthreads();
  {
    const char* src = (const char*)U;
    char* dst = (char*)Vcat + (size_t)row0 * 320;
    size_t lim = 96000000ULL - (size_t)row0 * 320;
#pragma unroll
    for (int j = 0; j < 15; ++j) {
      int byte = (j * 256 + t) * 16;
      if ((size_t)byte < lim)
        *(s16x8*)(dst + byte) = *(const s16x8*)(src + byte);
    }
  }
}

// ---------------------------------------------------------------------------
// K2: Vu GEMM. (unchanged from R4)
__global__ __launch_bounds__(256) void geo_gemm2(
    const short* __restrict__ Vcat, const short* __restrict__ WuTp,
    short* __restrict__ Vub) {
  __shared__ __align__(16) short Al[128 * 192];
  const int t = threadIdx.x;
  const int row0 = blockIdx.x << 7;
#pragma unroll
  for (int it = 0; it < 10; ++it) {
    int idx = it * 256 + t;
    int r = idx / 20, ch = idx - r * 20;
    int grow = row0 + r;
    s16x8 q = (s16x8){0, 0, 0, 0, 0, 0, 0, 0};
    if (grow < M3) q = *reinterpret_cast<const s16x8*>(&Vcat[(size_t)grow * 160 + ch * 8]);
    int off = r * 384 + ch * 16;
    *(s16x8*)((char*)Al + (off ^ ((r & 7) << 4))) = q;
  }
  __syncthreads();

  const int lane = t & 63, wv = t >> 6;
  const int wr = wv >> 1, wc = wv & 1;
  const int lr = lane & 15, lk = lane >> 4;
  f32x4 acc[4][4];
#pragma unroll
  for (int i = 0; i < 4; ++i)
#pragma unroll
    for (int j = 0; j < 4; ++j) acc[i][j] = (f32x4){0.f, 0.f, 0.f, 0.f};

#pragma unroll
  for (int kk = 0; kk < 5; ++kk) {
    s16x8 af[4], bq[4];
#pragma unroll
    for (int mi = 0; mi < 4; ++mi) {
      int row = wr * 64 + mi * 16 + lr;
      int off = row * 384 + (kk << 6) + (lk << 4);
      af[mi] = *(const s16x8*)((const char*)Al + (off ^ ((row & 7) << 4)));
    }
#pragma unroll
    for (int ni = 0; ni < 4; ++ni)
      bq[ni] = *reinterpret_cast<const s16x8*>(
          &WuTp[(wc * 64 + ni * 16 + lr) * 160 + (kk << 5) + (lk << 3)]);
#pragma unroll
    for (int mi = 0; mi < 4; ++mi)
#pragma unroll
      for (int ni = 0; ni < 4; ++ni)
        acc[mi][ni] = __builtin_amdgcn_mfma_f32_16x16x32_bf16(af[mi], bq[ni], acc[mi][ni], 0, 0, 0);
  }
#pragma unroll
  for (int mi = 0; mi < 4; ++mi)
#pragma unroll
    for (int ni = 0; ni < 4; ++ni) {
      int col = wc * 64 + ni * 16 + lr;
#pragma unroll
      for (int r = 0; r < 4; ++r) {
        int row = row0 + wr * 64 + mi * 16 + lk * 4 + r;
        if (row < M3) Vub[(size_t)row * 128 + col] = f2bf(acc[mi][ni][r]);
      }
    }
}

// ---------------------------------------------------------------------------
// K3: feats_out = silu(concat(feats, sh) @ Wf + bf).  M=100000, K=656(->704), N=512.
// 2-phase double-buffered: one barrier per K-step; A global loads issued a full
// body early (frA/frB two-deep reg pipeline); B via glds16, source-permuted for
// the (row>>1)&3 chunk swizzle (8 distinct 16B slots per 8-lane phase).
__global__ __launch_bounds__(256) void gemm_feats(
    const float* __restrict__ feats, const short* __restrict__ sh192,
    const short* __restrict__ WfT, const float* __restrict__ bfv,
    float* __restrict__ out) {
  const int bid = blockIdx.x;
  const int swz = (bid & 7) * 391 + (bid >> 3);
  const int mt = swz >> 2, nt = swz & 3;
  const int row0 = mt << 7, n0 = nt << 7;
  const int t = threadIdx.x;
  const int lane = t & 63, wv = t >> 6;
  const int wr = wv >> 1, wc = wv & 1;
  const int lr = lane & 15, lk = lane >> 4;

  __shared__ __align__(16) short Al[2][128 * 32];
  __shared__ __align__(16) short Bl[2][128 * 32];

  // A staging: thread owns row ar, k-half h (chunks 2h, 2h+1)
  const int ar = t >> 1, h = t & 1;
  const size_t arowc = (size_t)min(row0 + ar, BATCH - 1);
  const float* aFp = &feats[arowc * 512 + h * 16];
  const short* aSp = &sh192[arowc * 192 + h * 16];
  const int aw1 = SWOFF(ar, 2 * h), aw2 = SWOFF(ar, 2 * h + 1);

  // B staging: wave stages segs {2wv, 2wv+1}; lane slot l -> row s*16+(l>>2),
  // stored chunk (l&3) = c ^ ((l>>3)&3)
  const int bc = (lane & 3) ^ ((lane >> 3) & 3);
  const short* bSrc0 = &WfT[(size_t)(n0 + (wv * 2 + 0) * 16 + (lane >> 2)) * KP + bc * 8];
  const short* bSrc1 = &WfT[(size_t)(n0 + (wv * 2 + 1) * 16 + (lane >> 2)) * KP + bc * 8];

  f32x4 acc[4][4];
#pragma unroll
  for (int i = 0; i < 4; ++i)
#pragma unroll
    for (int j = 0; j < 4; ++j) acc[i][j] = (f32x4){0.f, 0.f, 0.f, 0.f};

  fl4 frA[4], frB[4];
  s16x8 sA0, sA1, sB0, sB1;

  auto issueA = [&](int ks, fl4* fr, s16x8& s0, s16x8& s1) {
    const int k0 = ks << 5;
    if (k0 < 512) {
#pragma unroll
      for (int j = 0; j < 4; ++j) fr[j] = *reinterpret_cast<const fl4*>(aFp + k0 + j * 4);
    } else {
      s0 = *reinterpret_cast<const s16x8*>(aSp + (k0 - 512));
      s1 = *reinterpret_cast<const s16x8*>(aSp + (k0 - 512) + 8);
    }
  };
  auto commitA = [&](int ks, int buf, const fl4* fr, const s16x8& s0, const s16x8& s1) {
    s16x8 lo, hi;
    if ((ks << 5) < 512) { lo = pack8(fr[0], fr[1]); hi = pack8(fr[2], fr[3]); }
    else { lo = s0; hi = s1; }
    *(s16x8*)&Al[buf][aw1] = lo;
    *(s16x8*)&Al[buf][aw2] = hi;
  };
  auto gldsB = [&](int ks, int buf) {
    const int k0 = ks << 5;
    glds16(bSrc0 + k0, &Bl[buf][(wv * 2 + 0) * 512]);
    glds16(bSrc1 + k0, &Bl[buf][(wv * 2 + 1) * 512]);
  };
  auto compute = [&](int buf) {
    s16x8 af[4], bq[4];
#pragma unroll
    for (int mi = 0; mi < 4; ++mi) {
      int rw = wr * 64 + mi * 16 + lr;
      af[mi] = *(const s16x8*)&Al[buf][SWOFF(rw, lk)];
    }
#pragma unroll
    for (int ni = 0; ni < 4; ++ni) {
      int rw = wc * 64 + ni * 16 + lr;
      bq[ni] = *(const s16x8*)&Bl[buf][SWOFF(rw, lk)];
    }
#pragma unroll
    for (int mi = 0; mi < 4; ++mi)
#pragma unroll
      for (int ni = 0; ni < 4; ++ni)
        acc[mi][ni] = __builtin_amdgcn_mfma_f32_16x16x32_bf16(af[mi], bq[ni], acc[mi][ni], 0, 0, 0);
  };

  // prologue
  issueA(0, frA, sA0, sA1);
  commitA(0, 0, frA, sA0, sA1);
  gldsB(0, 0);
  issueA(1, frB, sB0, sB1);
  __syncthreads();

  for (int ks = 0; ks < 22; ks += 2) {
    // even body: compute tile ks (buf0); stage tile ks+1 (buf1); issue A ks+2
    if (ks + 2 < 22) issueA(ks + 2, frA, sA0, sA1);
    if (ks + 1 < 22) { commitA(ks + 1, 1, frB, sB0, sB1); gldsB(ks + 1, 1); }
    compute(0);
    __syncthreads();
    // odd body: compute tile ks+1 (buf1); stage tile ks+2 (buf0); issue A ks+3
    if (ks + 3 < 22) issueA(ks + 3, frB, sB0, sB1);
    if (ks + 2 < 22) { commitA(ks + 2, 0, frA, sA0, sA1); gldsB(ks + 2, 0); }
    if (ks + 1 < 22) compute(1);
    __syncthreads();
  }

#pragma unroll
  for (int ni = 0; ni < 4; ++ni) {
    int col = n0 + wc * 64 + ni * 16 + lr;
    float bb = bfv[col];
#pragma unroll
    for (int mi = 0; mi < 4; ++mi) {
      int rbase = row0 + wr * 64 + mi * 16 + lk * 4;
#pragma unroll
      for (int rr = 0; rr < 4; ++rr) {
        int gr = rbase + rr;
        if (gr < BATCH) {
          float x = acc[mi][ni][rr] + bb;
          out[(size_t)gr * 512 + col] = x / (1.f + __expf(-x));
        }
      }
    }
  }
}

// ---------------------------------------------------------------------------
// K4: gating GEMM + sigmoid*Vub -> vectors_out f32.  M=100000, K=512, N=128.
// Same 2-phase double-buffered structure, NT=16.
__global__ __launch_bounds__(256) void gemm_gate(
    const float* __restrict__ fo, const short* __restrict__ WgT,
    const float* __restrict__ bg, const short* __restrict__ Vub,
    float* __restrict__ out) {
  const int bid = blockIdx.x;
  const int xcd = bid & 7, bidx = bid >> 3;
  const int swz = (xcd < 6 ? xcd * 98 : 6 * 98 + (xcd - 6) * 97) + bidx;
  const int row0 = swz << 7;
  const int t = threadIdx.x;
  const int lane = t & 63, wv = t >> 6;
  const int wr = wv >> 1, wc = wv & 1;
  const int lr = lane & 15, lk = lane >> 4;

  __shared__ __align__(16) short Al[2][128 * 32];
  __shared__ __align__(16) short Bl[2][128 * 32];

  const int ar = t >> 1, h = t & 1;
  const size_t arowc = (size_t)min(row0 + ar, BATCH - 1);
  const float* aFp = &fo[arowc * 512 + h * 16];
  const int aw1 = SWOFF(ar, 2 * h), aw2 = SWOFF(ar, 2 * h + 1);

  const int bc = (lane & 3) ^ ((lane >> 3) & 3);
  const short* bSrc0 = &WgT[(size_t)((wv * 2 + 0) * 16 + (lane >> 2)) * 512 + bc * 8];
  const short* bSrc1 = &WgT[(size_t)((wv * 2 + 1) * 16 + (lane >> 2)) * 512 + bc * 8];

  f32x4 acc[4][4];
#pragma unroll
  for (int i = 0; i < 4; ++i)
#pragma unroll
    for (int j = 0; j < 4; ++j) acc[i][j] = (f32x4){0.f, 0.f, 0.f, 0.f};

  fl4 frA[4], frB[4];

  auto issueA = [&](int ks, fl4* fr) {
    const int k0 = ks << 5;
#pragma unroll
    for (int j = 0; j < 4; ++j) fr[j] = *reinterpret_cast<const fl4*>(aFp + k0 + j * 4);
  };
  auto commitA = [&](int buf, const fl4* fr) {
    *(s16x8*)&Al[buf][aw1] = pack8(fr[0], fr[1]);
    *(s16x8*)&Al[buf][aw2] = pack8(fr[2], fr[3]);
  };
  auto gldsB = [&](int ks, int buf) {
    const int k0 = ks << 5;
    glds16(bSrc0 + k0, &Bl[buf][(wv * 2 + 0) * 512]);
    glds16(bSrc1 + k0, &Bl[buf][(wv * 2 + 1) * 512]);
  };
  auto compute = [&](int buf) {
    s16x8 af[4], bq[4];
#pragma unroll
    for (int mi = 0; mi < 4; ++mi) {
      int rw = wr * 64 + mi * 16 + lr;
      af[mi] = *(const s16x8*)&Al[buf][SWOFF(rw, lk)];
    }
#pragma unroll
    for (int ni = 0; ni < 4; ++ni) {
      int rw = wc * 64 + ni * 16 + lr;
      bq[ni] = *(const s16x8*)&Bl[buf][SWOFF(rw, lk)];
    }
#pragma unroll
    for (int mi = 0; mi < 4; ++mi)
#pragma unroll
      for (int ni = 0; ni < 4; ++ni)
        acc[mi][ni] = __builtin_amdgcn_mfma_f32_16x16x32_bf16(af[mi], bq[ni], acc[mi][ni], 0, 0, 0);
  };

  issueA(0, frA);
  commitA(0, frA);
  gldsB(0, 0);
  issueA(1, frB);
  __syncthreads();

  for (int ks = 0; ks < 16; ks += 2) {
    if (ks + 2 < 16) issueA(ks + 2, frA);
    if (ks + 1 < 16) { commitA(1, frB); gldsB(ks + 1, 1); }
    compute(0);
    __syncthreads();
    if (ks + 3 < 16) issueA(ks + 3, frB);
    if (ks + 2 < 16) { commitA(0, frA); gldsB(ks + 2, 0); }
    if (ks + 1 < 16) compute(1);
    __syncthreads();
  }

#pragma unroll
  for (int ni = 0; ni < 4; ++ni) {
    int col = wc * 64 + ni * 16 + lr;
    float bb = bg[col];
#pragma unroll
    for (int mi = 0; mi < 4; ++mi) {
      int rbase = row0 + wr * 64 + mi * 16 + lk * 4;
#pragma unroll
      for (int rr = 0; rr < 4; ++rr) {
        int gr = rbase + rr;
        if (gr < BATCH) {
          float x = acc[mi][ni][rr] + bb;
          float gate = 1.f / (1.f + __expf(-x));
          size_t vb = (size_t)(3 * gr) * 128 + col;
          float* po = &out[VECBASE + ((size_t)gr * 128 + col) * 3];
          po[0] = gate * bf2f(Vub[vb]);
          po[1] = gate * bf2f(Vub[vb + 128]);
          po[2] = gate * bf2f(Vub[vb + 256]);
        }
      }
    }
  }
}

// ---------------------------------------------------------------------------
extern "C" void kernel_launch(void* const* d_in, const int* in_sizes, int n_in,
                              void* d_out, int out_size, void* d_ws, size_t ws_size,
                              hipStream_t stream) {
  const float* feats = (const float*)d_in[0];
  const float* vecs  = (const float*)d_in[1];
  const float* Wh    = (const float*)d_in[2];
  const float* Wcp   = (const float*)d_in[3];
  const float* Wu    = (const float*)d_in[4];
  const float* Wf    = (const float*)d_in[5];
  const float* bfv   = (const float*)d_in[6];
  const float* Wg    = (const float*)d_in[7];
  const float* bg    = (const float*)d_in[8];
  float* out = (float*)d_out;

  char* ws = (char*)d_ws;
  short* sh192 = (short*)ws;                               // 38,400,000 B
  short* Vub   = (short*)(ws + 38400000);                  // 76,800,000 B
  short* WfT   = (short*)(ws + 115200000);                 // 720,896 B
  short* WgT   = (short*)(ws + 115920896);                 // 131,072 B
  short* WB1   = (short*)(ws + 116051968);                 // 40,960 B
  short* WuTp  = (short*)(ws + 116092928);                 // 40,960 B

  short* Vcat = (short*)d_out;                             // [3B][160] bf16 (dead feats region)

  hipLaunchKernelGGL(prep_w,     dim3(1824), dim3(256), 0, stream, Wh, Wcp, Wu, Wf, Wg, WB1, WuTp, WfT, WgT);
  hipLaunchKernelGGL(geo_gemm1,  dim3(1563), dim3(256), 0, stream, vecs, WB1, Vcat, sh192);
  hipLaunchKernelGGL(geo_gemm2,  dim3(2344), dim3(256), 0, stream, Vcat, WuTp, Vub);
  hipLaunchKernelGGL(gemm_feats, dim3(3128), dim3(256), 0, stream, feats, sh192, WfT, bfv, out);
  hipLaunchKernelGGL(gemm_gate,  dim3(782),  dim3(256), 0, stream, out, WgT, bg, Vub, out);
}